// Round 7
// baseline (192.856 us; speedup 1.0000x reference)
//
#include <hip/hip_runtime.h>

// GatedEncoderLayer: B=16, I=2048, J=1024, K=1024, F=32
// out[row,k] = sum_f [ (sum_j x[row,j]*Wy[j,f]) * Wx[row%I,f] ] * Wz[k,f]
constexpr int kI = 2048;
constexpr int kJ = 1024;
constexpr int kK = 1024;
constexpr int kF = 32;
constexpr int kRows = 16 * 2048;        // 32768

// ---------------------------------------------------------------------------
// Stage 1: t[row,f] = (sum_j x[row,j]*Wy[j,f]) * Wx[row%I,f]
// R=8 rows/thread: 1 ds_read_b128 feeds 32 FMA (round-6 R=4 was still
// latency-bound). 512 blocks x 512 thr (8 waves); wave w owns rows
// [64*blk + 8w, +8); lane = (jo:8)x(fq:8). Thread: 8 rows, f-quad fq,
// j where ((j>>2)&7)==jo.  x loads: lanes jo=0..7 = 128 contiguous bytes
// per row (coalesced, 8-way fq broadcast). Wy chunked 256 j in LDS (32KB,
// 2 blocks/CU = 16 waves/CU). Ping-pong xa/xn prefetch keeps 8 loads in
// flight per full 128-FMA window. j-reduce = butterfly shfl_xor(8/16/32).
// ---------------------------------------------------------------------------
constexpr int kCJ = 256;                // j per staged chunk

#define LOADWIN(buf, jabs)                                              \
    _Pragma("unroll")                                                   \
    for (int r = 0; r < 8; ++r)                                         \
        buf[r] = *reinterpret_cast<const float4*>(                      \
            xrow0 + (size_t)r * kJ + (jabs));

#define COMPUTE(buf, winbase)                                           \
    _Pragma("unroll")                                                   \
    for (int u = 0; u < 4; ++u) {                                       \
        const float4 wv = *reinterpret_cast<const float4*>(             \
            &wyb[(winbase) + jo * 4 + u][f0]);                          \
        _Pragma("unroll")                                               \
        for (int r = 0; r < 8; ++r) {                                   \
            const float xs = (u == 0) ? buf[r].x : (u == 1) ? buf[r].y  \
                           : (u == 2) ? buf[r].z : buf[r].w;            \
            acc[r].x = fmaf(xs, wv.x, acc[r].x);                        \
            acc[r].y = fmaf(xs, wv.y, acc[r].y);                        \
            acc[r].z = fmaf(xs, wv.z, acc[r].z);                        \
            acc[r].w = fmaf(xs, wv.w, acc[r].w);                        \
        }                                                               \
    }

__global__ __launch_bounds__(512, 4)
void ge_stage1(const float* __restrict__ x,
               const float* __restrict__ Wx,
               const float* __restrict__ Wy,
               float* __restrict__ t)
{
    __shared__ float wyb[kCJ][kF];      // 32 KiB

    const int tid  = threadIdx.x;
    const int lane = tid & 63;
    const int w    = tid >> 6;          // wave 0..7
    const int fq   = lane & 7;
    const int jo   = lane >> 3;         // 0..7
    const int f0   = fq * 4;
    const int rowBase = blockIdx.x * 64 + w * 8;

    const float* __restrict__ xrow0 = x + (size_t)rowBase * kJ + jo * 4;

    float4 acc[8];
#pragma unroll
    for (int r = 0; r < 8; ++r) acc[r] = make_float4(0.f, 0.f, 0.f, 0.f);

    float4 xa[8], xn[8];
    LOADWIN(xa, 0)                      // chunk 0, window 0 (in flight early)

    for (int c = 0; c < kJ / kCJ; ++c) {
        __syncthreads();                // previous chunk's readers done
        {   // stage 256x32 floats = 2048 float4 / 512 thr = 4 each
            const float4* src = reinterpret_cast<const float4*>(
                Wy + (size_t)c * kCJ * kF);
            float4* dst = reinterpret_cast<float4*>(&wyb[0][0]);
#pragma unroll
            for (int p = 0; p < 4; ++p)
                dst[tid + p * 512] = src[tid + p * 512];
        }
        __syncthreads();

        const int jc = c * kCJ;
#pragma unroll
        for (int wp = 0; wp < 4; ++wp) {          // 2 windows per pair
            LOADWIN(xn, jc + wp * 64 + 32)
            COMPUTE(xa, wp * 64)
            if (wp < 3) {
                LOADWIN(xa, jc + wp * 64 + 64)
            } else if (c < kJ / kCJ - 1) {
                LOADWIN(xa, jc + kCJ)             // next chunk, window 0
            }
            COMPUTE(xn, wp * 64 + 32)
        }
    }

    // butterfly reduce over jo lanes (bits 3..5), then lane jo writes row jo
    float4 ov = make_float4(0.f, 0.f, 0.f, 0.f);
#pragma unroll
    for (int r = 0; r < 8; ++r) {
        float4 v = acc[r];
        v.x += __shfl_xor(v.x, 8);
        v.y += __shfl_xor(v.y, 8);
        v.z += __shfl_xor(v.z, 8);
        v.w += __shfl_xor(v.w, 8);
        v.x += __shfl_xor(v.x, 16);
        v.y += __shfl_xor(v.y, 16);
        v.z += __shfl_xor(v.z, 16);
        v.w += __shfl_xor(v.w, 16);
        v.x += __shfl_xor(v.x, 32);
        v.y += __shfl_xor(v.y, 32);
        v.z += __shfl_xor(v.z, 32);
        v.w += __shfl_xor(v.w, 32);
        if (jo == r) ov = v;            // static-unrolled predicated select
    }

    const int row = rowBase + jo;
    const int i   = row & (kI - 1);
    const float4 g = *reinterpret_cast<const float4*>(Wx + (size_t)i * kF + f0);
    ov.x *= g.x; ov.y *= g.y; ov.z *= g.z; ov.w *= g.w;
    *reinterpret_cast<float4*>(t + (size_t)row * kF + f0) = ov;
}

// ---------------------------------------------------------------------------
// Stage 2: out[row,k] = sum_f t[row,f] * Wz[k,f]   (~28 us measured)
// 512 blocks x 512 threads, 64 rows/block, thread owns 2 k-columns with Wz
// in 64 VGPRs. launch_bounds(512,2): the (512,4) variant spilled (round 4).
// ---------------------------------------------------------------------------
__global__ __launch_bounds__(512, 2)
void ge_stage2(const float* __restrict__ t,
               const float* __restrict__ Wz,
               float* __restrict__ out)
{
    __shared__ float t2[64][kF];                       // 8 KiB = 512 float4

    const int tid = threadIdx.x;
    const int rowBase = blockIdx.x * 64;

    reinterpret_cast<float4*>(&t2[0][0])[tid] =
        reinterpret_cast<const float4*>(t + (size_t)rowBase * kF)[tid];

    const int k0 = tid * 2;
    float4 wa[8], wb[8];
#pragma unroll
    for (int q = 0; q < 8; ++q) {
        wa[q] = *reinterpret_cast<const float4*>(Wz + (size_t)k0 * kF + q * 4);
        wb[q] = *reinterpret_cast<const float4*>(Wz + (size_t)(k0 + 1) * kF + q * 4);
    }
    __syncthreads();

    float* __restrict__ orow = out + (size_t)rowBase * kK + k0;

    for (int r = 0; r < 64; ++r) {
        float4 tr[8];
#pragma unroll
        for (int q = 0; q < 8; ++q)
            tr[q] = *reinterpret_cast<const float4*>(&t2[r][q * 4]);

        float a0 = 0.f, a1 = 0.f, b0 = 0.f, b1 = 0.f;
#pragma unroll
        for (int q = 0; q < 8; q += 2) {
            a0 = fmaf(tr[q].x, wa[q].x, a0);
            a0 = fmaf(tr[q].y, wa[q].y, a0);
            a0 = fmaf(tr[q].z, wa[q].z, a0);
            a0 = fmaf(tr[q].w, wa[q].w, a0);
            a1 = fmaf(tr[q + 1].x, wa[q + 1].x, a1);
            a1 = fmaf(tr[q + 1].y, wa[q + 1].y, a1);
            a1 = fmaf(tr[q + 1].z, wa[q + 1].z, a1);
            a1 = fmaf(tr[q + 1].w, wa[q + 1].w, a1);
            b0 = fmaf(tr[q].x, wb[q].x, b0);
            b0 = fmaf(tr[q].y, wb[q].y, b0);
            b0 = fmaf(tr[q].z, wb[q].z, b0);
            b0 = fmaf(tr[q].w, wb[q].w, b0);
            b1 = fmaf(tr[q + 1].x, wb[q + 1].x, b1);
            b1 = fmaf(tr[q + 1].y, wb[q + 1].y, b1);
            b1 = fmaf(tr[q + 1].z, wb[q + 1].z, b1);
            b1 = fmaf(tr[q + 1].w, wb[q + 1].w, b1);
        }
        float2 o;
        o.x = a0 + a1;
        o.y = b0 + b1;
        *reinterpret_cast<float2*>(orow + (size_t)r * kK) = o;
    }
}

// ---------------------------------------------------------------------------
// Fallback: round-1 fused kernel (proven correct) if ws too small.
// ---------------------------------------------------------------------------
__global__ __launch_bounds__(256, 2)
void gated_encoder_fused(const float* __restrict__ x,
                         const float* __restrict__ Wx,
                         const float* __restrict__ Wy,
                         const float* __restrict__ Wz,
                         float* __restrict__ out)
{
    __shared__ float t2[64][kF + 4];

    const int tid  = threadIdx.x;
    const int lane = tid & 63;
    const int wv   = tid >> 6;

    const int rloc = wv * 16 + (lane >> 2);
    const int row  = blockIdx.x * 64 + rloc;
    const int fg8  = (lane & 3) * 8;

    const float* __restrict__ xrow = x + (size_t)row * kJ;

    float acc[8];
#pragma unroll
    for (int u = 0; u < 8; ++u) acc[u] = 0.0f;

    for (int j = 0; j < kJ; j += 8) {
        const float4 xv0 = *reinterpret_cast<const float4*>(xrow + j);
        const float4 xv1 = *reinterpret_cast<const float4*>(xrow + j + 4);
        const float xs[8] = {xv0.x, xv0.y, xv0.z, xv0.w,
                             xv1.x, xv1.y, xv1.z, xv1.w};
#pragma unroll
        for (int u = 0; u < 8; ++u) {
            const float* wyp = Wy + (size_t)(j + u) * kF + fg8;
            const float4 w0 = *reinterpret_cast<const float4*>(wyp);
            const float4 w1 = *reinterpret_cast<const float4*>(wyp + 4);
            acc[0] = fmaf(xs[u], w0.x, acc[0]);
            acc[1] = fmaf(xs[u], w0.y, acc[1]);
            acc[2] = fmaf(xs[u], w0.z, acc[2]);
            acc[3] = fmaf(xs[u], w0.w, acc[3]);
            acc[4] = fmaf(xs[u], w1.x, acc[4]);
            acc[5] = fmaf(xs[u], w1.y, acc[5]);
            acc[6] = fmaf(xs[u], w1.z, acc[6]);
            acc[7] = fmaf(xs[u], w1.w, acc[7]);
        }
    }

    const int i = row & (kI - 1);
    const float* wxp = Wx + (size_t)i * kF + fg8;
    const float4 g0 = *reinterpret_cast<const float4*>(wxp);
    const float4 g1 = *reinterpret_cast<const float4*>(wxp + 4);
    float4 r0, r1;
    r0.x = acc[0] * g0.x;  r0.y = acc[1] * g0.y;
    r0.z = acc[2] * g0.z;  r0.w = acc[3] * g0.w;
    r1.x = acc[4] * g1.x;  r1.y = acc[5] * g1.y;
    r1.z = acc[6] * g1.z;  r1.w = acc[7] * g1.w;
    *reinterpret_cast<float4*>(&t2[rloc][fg8])     = r0;
    *reinterpret_cast<float4*>(&t2[rloc][fg8 + 4]) = r1;

    __syncthreads();

    const size_t outBase = (size_t)blockIdx.x * 64 * kK;

#pragma unroll
    for (int pass = 0; pass < 2; ++pass) {
        const int k1 = pass * 512 + tid;
        const int k2 = k1 + 256;
        const float* wz1 = Wz + (size_t)k1 * kF;
        const float* wz2 = Wz + (size_t)k2 * kF;
        float4 z1[8], z2[8];
#pragma unroll
        for (int m = 0; m < 8; ++m) {
            z1[m] = *reinterpret_cast<const float4*>(wz1 + 4 * m);
            z2[m] = *reinterpret_cast<const float4*>(wz2 + 4 * m);
        }
        for (int r = 0; r < 64; ++r) {
            float4 a1 = {0.f, 0.f, 0.f, 0.f};
            float4 a2 = {0.f, 0.f, 0.f, 0.f};
#pragma unroll
            for (int m = 0; m < 8; ++m) {
                const float4 tv = *reinterpret_cast<const float4*>(&t2[r][4 * m]);
                a1.x = fmaf(tv.x, z1[m].x, a1.x);
                a1.y = fmaf(tv.y, z1[m].y, a1.y);
                a1.z = fmaf(tv.z, z1[m].z, a1.z);
                a1.w = fmaf(tv.w, z1[m].w, a1.w);
                a2.x = fmaf(tv.x, z2[m].x, a2.x);
                a2.y = fmaf(tv.y, z2[m].y, a2.y);
                a2.z = fmaf(tv.z, z2[m].z, a2.z);
                a2.w = fmaf(tv.w, z2[m].w, a2.w);
            }
            out[outBase + (size_t)r * kK + k1] = (a1.x + a1.y) + (a1.z + a1.w);
            out[outBase + (size_t)r * kK + k2] = (a2.x + a2.y) + (a2.z + a2.w);
        }
    }
}

extern "C" void kernel_launch(void* const* d_in, const int* in_sizes, int n_in,
                              void* d_out, int out_size, void* d_ws, size_t ws_size,
                              hipStream_t stream) {
    const float* x  = (const float*)d_in[0];   // (B, I, J)
    const float* Wx = (const float*)d_in[1];   // (I, F)
    const float* Wy = (const float*)d_in[2];   // (J, F)
    const float* Wz = (const float*)d_in[3];   // (K, F)
    float* out = (float*)d_out;                // (B, I, K) f32

    const size_t tBytes = (size_t)kRows * kF * sizeof(float);   // 4 MiB

    if (ws_size >= tBytes && d_ws != nullptr) {
        float* t = (float*)d_ws;
        ge_stage1<<<dim3(kRows / 64), 512, 0, stream>>>(x, Wx, Wy, t);
        ge_stage2<<<dim3(kRows / 64), 512, 0, stream>>>(t, Wz, out);
    } else {
        gated_encoder_fused<<<dim3(kRows / 64), 256, 0, stream>>>(x, Wx, Wy, Wz, out);
    }
}

// Round 8
// 136.724 us; speedup vs baseline: 1.4105x; 1.4105x over previous
//
#include <hip/hip_runtime.h>

// GatedEncoderLayer: B=16, I=2048, J=1024, K=1024, F=32
// out[row,k] = sum_f [ (sum_j x[row,j]*Wy[j,f]) * Wx[row%I,f] ] * Wz[k,f]
constexpr int kI = 2048;
constexpr int kJ = 1024;
constexpr int kK = 1024;
constexpr int kF = 32;
constexpr int kRows = 16 * 2048;        // 32768

// ---------------------------------------------------------------------------
// Stage 1: t[row,f] = (sum_j x[row,j]*Wy[j,f]) * Wx[row%I,f]
// R=8 rows/thread: 1 ds_read_b128 feeds 32 FMA. 512 blocks x 512 thr;
// wave w owns rows [64*blk + 8w, +8); lane = (jo:8)x(fq:8).
// x loads: 8 consecutive 16B quads per row per instr (coalesced, 8-way bcast).
// Wy chunked 256 j in LDS (32KB), XOR-swizzled: quad = j*8 + (fq ^ ((j>>2)&7))
//   -> round-7's 8-way read conflict (2.1M) eliminated (conflict set is
//      fixed-fq across jo; key must come from j>>2).
// launch_bounds(512,2): 128 VGPR cap. (512,4) empirically caps at 64 VGPR
//   and spilled acc/xa/xn (WRITE_SIZE 158MB, round 7).
// Ping-pong xa/xn prefetch; j-reduce = butterfly shfl_xor(8/16/32).
// ---------------------------------------------------------------------------
constexpr int kCJ = 256;                // j per staged chunk

#define LOADWIN(buf, jabs)                                              \
    _Pragma("unroll")                                                   \
    for (int r = 0; r < 8; ++r)                                         \
        buf[r] = *reinterpret_cast<const float4*>(                      \
            xrow0 + (size_t)r * kJ + (jabs));

#define COMPUTE(buf, winbase)                                           \
    _Pragma("unroll")                                                   \
    for (int u = 0; u < 4; ++u) {                                       \
        const int jl = (winbase) + jo * 4 + u;                          \
        const float4 wv = *reinterpret_cast<const float4*>(             \
            &wyb[(jl * 8 + (fq ^ ((jl >> 2) & 7))) * 4]);               \
        _Pragma("unroll")                                               \
        for (int r = 0; r < 8; ++r) {                                   \
            const float xs = (u == 0) ? buf[r].x : (u == 1) ? buf[r].y  \
                           : (u == 2) ? buf[r].z : buf[r].w;            \
            acc[r].x = fmaf(xs, wv.x, acc[r].x);                        \
            acc[r].y = fmaf(xs, wv.y, acc[r].y);                        \
            acc[r].z = fmaf(xs, wv.z, acc[r].z);                        \
            acc[r].w = fmaf(xs, wv.w, acc[r].w);                        \
        }                                                               \
    }

__global__ __launch_bounds__(512, 2)
void ge_stage1(const float* __restrict__ x,
               const float* __restrict__ Wx,
               const float* __restrict__ Wy,
               float* __restrict__ t)
{
    __shared__ float wyb[kCJ * kF];     // 32 KiB, 16B-swizzled layout

    const int tid  = threadIdx.x;
    const int lane = tid & 63;
    const int w    = tid >> 6;          // wave 0..7
    const int fq   = lane & 7;
    const int jo   = lane >> 3;         // 0..7
    const int rowBase = blockIdx.x * 64 + w * 8;

    const float* __restrict__ xrow0 = x + (size_t)rowBase * kJ + jo * 4;

    float4 acc[8];
#pragma unroll
    for (int r = 0; r < 8; ++r) acc[r] = make_float4(0.f, 0.f, 0.f, 0.f);

    float4 xa[8], xn[8];
    LOADWIN(xa, 0)                      // chunk 0, window 0 (in flight early)

    for (int c = 0; c < kJ / kCJ; ++c) {
        __syncthreads();                // previous chunk's readers done
        {   // stage 256x32 floats = 2048 float4 / 512 thr = 4 each, swizzled
            const float4* src = reinterpret_cast<const float4*>(
                Wy + (size_t)c * kCJ * kF);
            float4* dst = reinterpret_cast<float4*>(wyb);
#pragma unroll
            for (int p = 0; p < 4; ++p) {
                const int flat = tid + p * 512;
                dst[(flat & ~7) | ((flat ^ (flat >> 5)) & 7)] = src[flat];
            }
        }
        __syncthreads();

        const int jc = c * kCJ;
#pragma unroll
        for (int wp = 0; wp < 4; ++wp) {          // 2 windows per pair
            LOADWIN(xn, jc + wp * 64 + 32)
            COMPUTE(xa, wp * 64)
            if (wp < 3) {
                LOADWIN(xa, jc + wp * 64 + 64)
            } else if (c < kJ / kCJ - 1) {
                LOADWIN(xa, jc + kCJ)             // next chunk, window 0
            }
            COMPUTE(xn, wp * 64 + 32)
        }
    }

    // butterfly reduce over jo lanes (bits 3..5), then lane jo writes row jo
    float4 ov = make_float4(0.f, 0.f, 0.f, 0.f);
#pragma unroll
    for (int r = 0; r < 8; ++r) {
        float4 v = acc[r];
        v.x += __shfl_xor(v.x, 8);
        v.y += __shfl_xor(v.y, 8);
        v.z += __shfl_xor(v.z, 8);
        v.w += __shfl_xor(v.w, 8);
        v.x += __shfl_xor(v.x, 16);
        v.y += __shfl_xor(v.y, 16);
        v.z += __shfl_xor(v.z, 16);
        v.w += __shfl_xor(v.w, 16);
        v.x += __shfl_xor(v.x, 32);
        v.y += __shfl_xor(v.y, 32);
        v.z += __shfl_xor(v.z, 32);
        v.w += __shfl_xor(v.w, 32);
        if (jo == r) ov = v;            // static-unrolled predicated select
    }

    const int f0  = fq * 4;
    const int row = rowBase + jo;
    const int i   = row & (kI - 1);
    const float4 g = *reinterpret_cast<const float4*>(Wx + (size_t)i * kF + f0);
    ov.x *= g.x; ov.y *= g.y; ov.z *= g.z; ov.w *= g.w;
    *reinterpret_cast<float4*>(t + (size_t)row * kF + f0) = ov;
}

// ---------------------------------------------------------------------------
// Stage 2: out[row,k] = sum_f t[row,f] * Wz[k,f]   (~28 us measured)
// 512 blocks x 512 threads, 64 rows/block, thread owns 2 k-columns with Wz
// in 64 VGPRs. launch_bounds(512,2): the (512,4) variant spilled (round 4).
// ---------------------------------------------------------------------------
__global__ __launch_bounds__(512, 2)
void ge_stage2(const float* __restrict__ t,
               const float* __restrict__ Wz,
               float* __restrict__ out)
{
    __shared__ float t2[64][kF];                       // 8 KiB = 512 float4

    const int tid = threadIdx.x;
    const int rowBase = blockIdx.x * 64;

    reinterpret_cast<float4*>(&t2[0][0])[tid] =
        reinterpret_cast<const float4*>(t + (size_t)rowBase * kF)[tid];

    const int k0 = tid * 2;
    float4 wa[8], wb[8];
#pragma unroll
    for (int q = 0; q < 8; ++q) {
        wa[q] = *reinterpret_cast<const float4*>(Wz + (size_t)k0 * kF + q * 4);
        wb[q] = *reinterpret_cast<const float4*>(Wz + (size_t)(k0 + 1) * kF + q * 4);
    }
    __syncthreads();

    float* __restrict__ orow = out + (size_t)rowBase * kK + k0;

    for (int r = 0; r < 64; ++r) {
        float4 tr[8];
#pragma unroll
        for (int q = 0; q < 8; ++q)
            tr[q] = *reinterpret_cast<const float4*>(&t2[r][q * 4]);

        float a0 = 0.f, a1 = 0.f, b0 = 0.f, b1 = 0.f;
#pragma unroll
        for (int q = 0; q < 8; q += 2) {
            a0 = fmaf(tr[q].x, wa[q].x, a0);
            a0 = fmaf(tr[q].y, wa[q].y, a0);
            a0 = fmaf(tr[q].z, wa[q].z, a0);
            a0 = fmaf(tr[q].w, wa[q].w, a0);
            a1 = fmaf(tr[q + 1].x, wa[q + 1].x, a1);
            a1 = fmaf(tr[q + 1].y, wa[q + 1].y, a1);
            a1 = fmaf(tr[q + 1].z, wa[q + 1].z, a1);
            a1 = fmaf(tr[q + 1].w, wa[q + 1].w, a1);
            b0 = fmaf(tr[q].x, wb[q].x, b0);
            b0 = fmaf(tr[q].y, wb[q].y, b0);
            b0 = fmaf(tr[q].z, wb[q].z, b0);
            b0 = fmaf(tr[q].w, wb[q].w, b0);
            b1 = fmaf(tr[q + 1].x, wb[q + 1].x, b1);
            b1 = fmaf(tr[q + 1].y, wb[q + 1].y, b1);
            b1 = fmaf(tr[q + 1].z, wb[q + 1].z, b1);
            b1 = fmaf(tr[q + 1].w, wb[q + 1].w, b1);
        }
        float2 o;
        o.x = a0 + a1;
        o.y = b0 + b1;
        *reinterpret_cast<float2*>(orow + (size_t)r * kK) = o;
    }
}

// ---------------------------------------------------------------------------
// Fallback: round-1 fused kernel (proven correct) if ws too small.
// ---------------------------------------------------------------------------
__global__ __launch_bounds__(256, 2)
void gated_encoder_fused(const float* __restrict__ x,
                         const float* __restrict__ Wx,
                         const float* __restrict__ Wy,
                         const float* __restrict__ Wz,
                         float* __restrict__ out)
{
    __shared__ float t2[64][kF + 4];

    const int tid  = threadIdx.x;
    const int lane = tid & 63;
    const int wv   = tid >> 6;

    const int rloc = wv * 16 + (lane >> 2);
    const int row  = blockIdx.x * 64 + rloc;
    const int fg8  = (lane & 3) * 8;

    const float* __restrict__ xrow = x + (size_t)row * kJ;

    float acc[8];
#pragma unroll
    for (int u = 0; u < 8; ++u) acc[u] = 0.0f;

    for (int j = 0; j < kJ; j += 8) {
        const float4 xv0 = *reinterpret_cast<const float4*>(xrow + j);
        const float4 xv1 = *reinterpret_cast<const float4*>(xrow + j + 4);
        const float xs[8] = {xv0.x, xv0.y, xv0.z, xv0.w,
                             xv1.x, xv1.y, xv1.z, xv1.w};
#pragma unroll
        for (int u = 0; u < 8; ++u) {
            const float* wyp = Wy + (size_t)(j + u) * kF + fg8;
            const float4 w0 = *reinterpret_cast<const float4*>(wyp);
            const float4 w1 = *reinterpret_cast<const float4*>(wyp + 4);
            acc[0] = fmaf(xs[u], w0.x, acc[0]);
            acc[1] = fmaf(xs[u], w0.y, acc[1]);
            acc[2] = fmaf(xs[u], w0.z, acc[2]);
            acc[3] = fmaf(xs[u], w0.w, acc[3]);
            acc[4] = fmaf(xs[u], w1.x, acc[4]);
            acc[5] = fmaf(xs[u], w1.y, acc[5]);
            acc[6] = fmaf(xs[u], w1.z, acc[6]);
            acc[7] = fmaf(xs[u], w1.w, acc[7]);
        }
    }

    const int i = row & (kI - 1);
    const float* wxp = Wx + (size_t)i * kF + fg8;
    const float4 g0 = *reinterpret_cast<const float4*>(wxp);
    const float4 g1 = *reinterpret_cast<const float4*>(wxp + 4);
    float4 r0, r1;
    r0.x = acc[0] * g0.x;  r0.y = acc[1] * g0.y;
    r0.z = acc[2] * g0.z;  r0.w = acc[3] * g0.w;
    r1.x = acc[4] * g1.x;  r1.y = acc[5] * g1.y;
    r1.z = acc[6] * g1.z;  r1.w = acc[7] * g1.w;
    *reinterpret_cast<float4*>(&t2[rloc][fg8])     = r0;
    *reinterpret_cast<float4*>(&t2[rloc][fg8 + 4]) = r1;

    __syncthreads();

    const size_t outBase = (size_t)blockIdx.x * 64 * kK;

#pragma unroll
    for (int pass = 0; pass < 2; ++pass) {
        const int k1 = pass * 512 + tid;
        const int k2 = k1 + 256;
        const float* wz1 = Wz + (size_t)k1 * kF;
        const float* wz2 = Wz + (size_t)k2 * kF;
        float4 z1[8], z2[8];
#pragma unroll
        for (int m = 0; m < 8; ++m) {
            z1[m] = *reinterpret_cast<const float4*>(wz1 + 4 * m);
            z2[m] = *reinterpret_cast<const float4*>(wz2 + 4 * m);
        }
        for (int r = 0; r < 64; ++r) {
            float4 a1 = {0.f, 0.f, 0.f, 0.f};
            float4 a2 = {0.f, 0.f, 0.f, 0.f};
#pragma unroll
            for (int m = 0; m < 8; ++m) {
                const float4 tv = *reinterpret_cast<const float4*>(&t2[r][4 * m]);
                a1.x = fmaf(tv.x, z1[m].x, a1.x);
                a1.y = fmaf(tv.y, z1[m].y, a1.y);
                a1.z = fmaf(tv.z, z1[m].z, a1.z);
                a1.w = fmaf(tv.w, z1[m].w, a1.w);
                a2.x = fmaf(tv.x, z2[m].x, a2.x);
                a2.y = fmaf(tv.y, z2[m].y, a2.y);
                a2.z = fmaf(tv.z, z2[m].z, a2.z);
                a2.w = fmaf(tv.w, z2[m].w, a2.w);
            }
            out[outBase + (size_t)r * kK + k1] = (a1.x + a1.y) + (a1.z + a1.w);
            out[outBase + (size_t)r * kK + k2] = (a2.x + a2.y) + (a2.z + a2.w);
        }
    }
}

extern "C" void kernel_launch(void* const* d_in, const int* in_sizes, int n_in,
                              void* d_out, int out_size, void* d_ws, size_t ws_size,
                              hipStream_t stream) {
    const float* x  = (const float*)d_in[0];   // (B, I, J)
    const float* Wx = (const float*)d_in[1];   // (I, F)
    const float* Wy = (const float*)d_in[2];   // (J, F)
    const float* Wz = (const float*)d_in[3];   // (K, F)
    float* out = (float*)d_out;                // (B, I, K) f32

    const size_t tBytes = (size_t)kRows * kF * sizeof(float);   // 4 MiB

    if (ws_size >= tBytes && d_ws != nullptr) {
        float* t = (float*)d_ws;
        ge_stage1<<<dim3(kRows / 64), 512, 0, stream>>>(x, Wx, Wy, t);
        ge_stage2<<<dim3(kRows / 64), 512, 0, stream>>>(t, Wz, out);
    } else {
        gated_encoder_fused<<<dim3(kRows / 64), 256, 0, stream>>>(x, Wx, Wy, Wz, out);
    }
}

// Round 9
// 112.375 us; speedup vs baseline: 1.7162x; 1.2167x over previous
//
#include <hip/hip_runtime.h>

// GatedEncoderLayer: B=16, I=2048, J=1024, K=1024, F=32
// out[row,k] = sum_f [ (sum_j x[row,j]*Wy[j,f]) * Wx[row%I,f] ] * Wz[k,f]
constexpr int kI = 2048;
constexpr int kJ = 1024;
constexpr int kK = 1024;
constexpr int kF = 32;
constexpr int kRows = 16 * 2048;        // 32768

// ---------------------------------------------------------------------------
// Stage 1: t[row,f] = (sum_j x[row,j]*Wy[j,f]) * Wx[row%I,f]
// jo-split, R=4 rows/thread (1 ds_read_b128 feeds 16 FMA; LDS ~15us, benign).
// 1024 blocks x 512 thr; wave owns 4 rows; lane = (jo:8)x(fq:8).
// x loads: per instr 8 consecutive 16B quads of one row (coalesced, 8-way
//   fq-broadcast). Load-1-window-ahead ping-pong (xa/xb).
// Register budget (session law: VGPR_Count==cap => spill):
//   acc 16 + xa 16 + xb 16 + 4 addr pairs 8 + misc ~20 = ~80 < 128 cap
//   of launch_bounds(512,2).  R=8 needed ~125+ and spilled (rounds 7/8).
// Wy chunk = 512 j = 64 KB LDS -> 2 blocks/CU, only 2 chunk barriers.
// No LDS swizzle: round-8 showed the 2.1M "conflicts" are the unavoidable
//   64-distinct-quad delivery cost (~8k cyc/CU total) — not fixable, not
//   significant.  Chunk & window loops fully unrolled -> static reg indices.
// ---------------------------------------------------------------------------
constexpr int kCJ = 512;                // j per staged chunk

#define LOADW(buf, jabs)                                               \
    _Pragma("unroll")                                                  \
    for (int r = 0; r < 4; ++r)                                        \
        buf[r] = *reinterpret_cast<const float4*>(                     \
            xrow0 + (size_t)r * kJ + (jabs));

#define COMPW(buf, jl)                                                 \
    _Pragma("unroll")                                                  \
    for (int u = 0; u < 4; ++u) {                                      \
        const float4 wv = *reinterpret_cast<const float4*>(            \
            &wyb[(((jl) + jo * 4 + u) * 8 + fq) * 4]);                 \
        _Pragma("unroll")                                              \
        for (int r = 0; r < 4; ++r) {                                  \
            const float xs = (u == 0) ? buf[r].x : (u == 1) ? buf[r].y \
                           : (u == 2) ? buf[r].z : buf[r].w;           \
            acc[r].x = fmaf(xs, wv.x, acc[r].x);                       \
            acc[r].y = fmaf(xs, wv.y, acc[r].y);                       \
            acc[r].z = fmaf(xs, wv.z, acc[r].z);                       \
            acc[r].w = fmaf(xs, wv.w, acc[r].w);                       \
        }                                                              \
    }

__global__ __launch_bounds__(512, 2)
void ge_stage1(const float* __restrict__ x,
               const float* __restrict__ Wx,
               const float* __restrict__ Wy,
               float* __restrict__ t)
{
    __shared__ float wyb[kCJ * kF];     // 64 KiB, linear [j][f]

    const int tid  = threadIdx.x;
    const int lane = tid & 63;
    const int w    = tid >> 6;          // wave 0..7
    const int fq   = lane & 7;
    const int jo   = lane >> 3;         // 0..7
    const int rowBase = blockIdx.x * 32 + w * 4;

    const float* __restrict__ xrow0 = x + (size_t)rowBase * kJ + jo * 4;

    float4 acc[4];
#pragma unroll
    for (int r = 0; r < 4; ++r) acc[r] = make_float4(0.f, 0.f, 0.f, 0.f);

    float4 xa[4], xb[4];
    LOADW(xa, 0)                        // window 0 in flight early

#pragma unroll
    for (int c = 0; c < 2; ++c) {
        __syncthreads();                // previous chunk's readers done
        {   // stage 512x32 floats = 4096 float4 / 512 thr = 8 each, linear
            const float4* src = reinterpret_cast<const float4*>(
                Wy + (size_t)c * kCJ * kF);
            float4* dst = reinterpret_cast<float4*>(wyb);
#pragma unroll
            for (int p = 0; p < 8; ++p)
                dst[tid + p * 512] = src[tid + p * 512];
        }
        __syncthreads();

#pragma unroll
        for (int wd = 0; wd < 16; ++wd) {
            const int gw = c * 16 + wd;           // global window 0..31
            if ((gw & 1) == 0) {
                if (gw < 31) { LOADW(xb, (gw + 1) * 32) }   // next window
                COMPW(xa, wd * 32)
            } else {
                if (gw < 31) { LOADW(xa, (gw + 1) * 32) }
                COMPW(xb, wd * 32)
            }
        }
        // cross-chunk prefetch: gw=15 loads j=512 (next chunk window 0);
        // the barrier drains vmcnt but the loaded VALUES stay valid in regs.
    }

    // butterfly reduce over jo lanes (bits 3..5); lane jo==r takes row r
    float4 ov = make_float4(0.f, 0.f, 0.f, 0.f);
#pragma unroll
    for (int r = 0; r < 4; ++r) {
        float4 v = acc[r];
        v.x += __shfl_xor(v.x, 8);
        v.y += __shfl_xor(v.y, 8);
        v.z += __shfl_xor(v.z, 8);
        v.w += __shfl_xor(v.w, 8);
        v.x += __shfl_xor(v.x, 16);
        v.y += __shfl_xor(v.y, 16);
        v.z += __shfl_xor(v.z, 16);
        v.w += __shfl_xor(v.w, 16);
        v.x += __shfl_xor(v.x, 32);
        v.y += __shfl_xor(v.y, 32);
        v.z += __shfl_xor(v.z, 32);
        v.w += __shfl_xor(v.w, 32);
        if (jo == r) ov = v;            // static-unrolled predicated select
    }

    if (jo < 4) {
        const int f0  = fq * 4;
        const int row = rowBase + jo;
        const int i   = row & (kI - 1);
        const float4 g = *reinterpret_cast<const float4*>(
            Wx + (size_t)i * kF + f0);
        ov.x *= g.x; ov.y *= g.y; ov.z *= g.z; ov.w *= g.w;
        *reinterpret_cast<float4*>(t + (size_t)row * kF + f0) = ov;
    }
}

// ---------------------------------------------------------------------------
// Stage 2: out[row,k] = sum_f t[row,f] * Wz[k,f]   (~28 us measured, round 5)
// 512 blocks x 512 threads, 64 rows/block, thread owns 2 k-columns with Wz
// in 64 VGPRs. launch_bounds(512,2): the (512,4) variant spilled (round 4).
// ---------------------------------------------------------------------------
__global__ __launch_bounds__(512, 2)
void ge_stage2(const float* __restrict__ t,
               const float* __restrict__ Wz,
               float* __restrict__ out)
{
    __shared__ float t2[64][kF];                       // 8 KiB = 512 float4

    const int tid = threadIdx.x;
    const int rowBase = blockIdx.x * 64;

    reinterpret_cast<float4*>(&t2[0][0])[tid] =
        reinterpret_cast<const float4*>(t + (size_t)rowBase * kF)[tid];

    const int k0 = tid * 2;
    float4 wa[8], wb[8];
#pragma unroll
    for (int q = 0; q < 8; ++q) {
        wa[q] = *reinterpret_cast<const float4*>(Wz + (size_t)k0 * kF + q * 4);
        wb[q] = *reinterpret_cast<const float4*>(Wz + (size_t)(k0 + 1) * kF + q * 4);
    }
    __syncthreads();

    float* __restrict__ orow = out + (size_t)rowBase * kK + k0;

    for (int r = 0; r < 64; ++r) {
        float4 tr[8];
#pragma unroll
        for (int q = 0; q < 8; ++q)
            tr[q] = *reinterpret_cast<const float4*>(&t2[r][q * 4]);

        float a0 = 0.f, a1 = 0.f, b0 = 0.f, b1 = 0.f;
#pragma unroll
        for (int q = 0; q < 8; q += 2) {
            a0 = fmaf(tr[q].x, wa[q].x, a0);
            a0 = fmaf(tr[q].y, wa[q].y, a0);
            a0 = fmaf(tr[q].z, wa[q].z, a0);
            a0 = fmaf(tr[q].w, wa[q].w, a0);
            a1 = fmaf(tr[q + 1].x, wa[q + 1].x, a1);
            a1 = fmaf(tr[q + 1].y, wa[q + 1].y, a1);
            a1 = fmaf(tr[q + 1].z, wa[q + 1].z, a1);
            a1 = fmaf(tr[q + 1].w, wa[q + 1].w, a1);
            b0 = fmaf(tr[q].x, wb[q].x, b0);
            b0 = fmaf(tr[q].y, wb[q].y, b0);
            b0 = fmaf(tr[q].z, wb[q].z, b0);
            b0 = fmaf(tr[q].w, wb[q].w, b0);
            b1 = fmaf(tr[q + 1].x, wb[q + 1].x, b1);
            b1 = fmaf(tr[q + 1].y, wb[q + 1].y, b1);
            b1 = fmaf(tr[q + 1].z, wb[q + 1].z, b1);
            b1 = fmaf(tr[q + 1].w, wb[q + 1].w, b1);
        }
        float2 o;
        o.x = a0 + a1;
        o.y = b0 + b1;
        *reinterpret_cast<float2*>(orow + (size_t)r * kK) = o;
    }
}

// ---------------------------------------------------------------------------
// Fallback: round-1 fused kernel (proven correct) if ws too small.
// ---------------------------------------------------------------------------
__global__ __launch_bounds__(256, 2)
void gated_encoder_fused(const float* __restrict__ x,
                         const float* __restrict__ Wx,
                         const float* __restrict__ Wy,
                         const float* __restrict__ Wz,
                         float* __restrict__ out)
{
    __shared__ float t2[64][kF + 4];

    const int tid  = threadIdx.x;
    const int lane = tid & 63;
    const int wv   = tid >> 6;

    const int rloc = wv * 16 + (lane >> 2);
    const int row  = blockIdx.x * 64 + rloc;
    const int fg8  = (lane & 3) * 8;

    const float* __restrict__ xrow = x + (size_t)row * kJ;

    float acc[8];
#pragma unroll
    for (int u = 0; u < 8; ++u) acc[u] = 0.0f;

    for (int j = 0; j < kJ; j += 8) {
        const float4 xv0 = *reinterpret_cast<const float4*>(xrow + j);
        const float4 xv1 = *reinterpret_cast<const float4*>(xrow + j + 4);
        const float xs[8] = {xv0.x, xv0.y, xv0.z, xv0.w,
                             xv1.x, xv1.y, xv1.z, xv1.w};
#pragma unroll
        for (int u = 0; u < 8; ++u) {
            const float* wyp = Wy + (size_t)(j + u) * kF + fg8;
            const float4 w0 = *reinterpret_cast<const float4*>(wyp);
            const float4 w1 = *reinterpret_cast<const float4*>(wyp + 4);
            acc[0] = fmaf(xs[u], w0.x, acc[0]);
            acc[1] = fmaf(xs[u], w0.y, acc[1]);
            acc[2] = fmaf(xs[u], w0.z, acc[2]);
            acc[3] = fmaf(xs[u], w0.w, acc[3]);
            acc[4] = fmaf(xs[u], w1.x, acc[4]);
            acc[5] = fmaf(xs[u], w1.y, acc[5]);
            acc[6] = fmaf(xs[u], w1.z, acc[6]);
            acc[7] = fmaf(xs[u], w1.w, acc[7]);
        }
    }

    const int i = row & (kI - 1);
    const float* wxp = Wx + (size_t)i * kF + fg8;
    const float4 g0 = *reinterpret_cast<const float4*>(wxp);
    const float4 g1 = *reinterpret_cast<const float4*>(wxp + 4);
    float4 r0, r1;
    r0.x = acc[0] * g0.x;  r0.y = acc[1] * g0.y;
    r0.z = acc[2] * g0.z;  r0.w = acc[3] * g0.w;
    r1.x = acc[4] * g1.x;  r1.y = acc[5] * g1.y;
    r1.z = acc[6] * g1.z;  r1.w = acc[7] * g1.w;
    *reinterpret_cast<float4*>(&t2[rloc][fg8])     = r0;
    *reinterpret_cast<float4*>(&t2[rloc][fg8 + 4]) = r1;

    __syncthreads();

    const size_t outBase = (size_t)blockIdx.x * 64 * kK;

#pragma unroll
    for (int pass = 0; pass < 2; ++pass) {
        const int k1 = pass * 512 + tid;
        const int k2 = k1 + 256;
        const float* wz1 = Wz + (size_t)k1 * kF;
        const float* wz2 = Wz + (size_t)k2 * kF;
        float4 z1[8], z2[8];
#pragma unroll
        for (int m = 0; m < 8; ++m) {
            z1[m] = *reinterpret_cast<const float4*>(wz1 + 4 * m);
            z2[m] = *reinterpret_cast<const float4*>(wz2 + 4 * m);
        }
        for (int r = 0; r < 64; ++r) {
            float4 a1 = {0.f, 0.f, 0.f, 0.f};
            float4 a2 = {0.f, 0.f, 0.f, 0.f};
#pragma unroll
            for (int m = 0; m < 8; ++m) {
                const float4 tv = *reinterpret_cast<const float4*>(&t2[r][4 * m]);
                a1.x = fmaf(tv.x, z1[m].x, a1.x);
                a1.y = fmaf(tv.y, z1[m].y, a1.y);
                a1.z = fmaf(tv.z, z1[m].z, a1.z);
                a1.w = fmaf(tv.w, z1[m].w, a1.w);
                a2.x = fmaf(tv.x, z2[m].x, a2.x);
                a2.y = fmaf(tv.y, z2[m].y, a2.y);
                a2.z = fmaf(tv.z, z2[m].z, a2.z);
                a2.w = fmaf(tv.w, z2[m].w, a2.w);
            }
            out[outBase + (size_t)r * kK + k1] = (a1.x + a1.y) + (a1.z + a1.w);
            out[outBase + (size_t)r * kK + k2] = (a2.x + a2.y) + (a2.z + a2.w);
        }
    }
}

extern "C" void kernel_launch(void* const* d_in, const int* in_sizes, int n_in,
                              void* d_out, int out_size, void* d_ws, size_t ws_size,
                              hipStream_t stream) {
    const float* x  = (const float*)d_in[0];   // (B, I, J)
    const float* Wx = (const float*)d_in[1];   // (I, F)
    const float* Wy = (const float*)d_in[2];   // (J, F)
    const float* Wz = (const float*)d_in[3];   // (K, F)
    float* out = (float*)d_out;                // (B, I, K) f32

    const size_t tBytes = (size_t)kRows * kF * sizeof(float);   // 4 MiB

    if (ws_size >= tBytes && d_ws != nullptr) {
        float* t = (float*)d_ws;
        ge_stage1<<<dim3(kRows / 32), 512, 0, stream>>>(x, Wx, Wy, t);
        ge_stage2<<<dim3(kRows / 64), 512, 0, stream>>>(t, Wz, out);
    } else {
        gated_encoder_fused<<<dim3(kRows / 64), 256, 0, stream>>>(x, Wx, Wy, Wz, out);
    }
}

// Round 10
// 108.083 us; speedup vs baseline: 1.7843x; 1.0397x over previous
//
#include <hip/hip_runtime.h>

// GatedEncoderLayer: B=16, I=2048, J=1024, K=1024, F=32
// out[row,k] = sum_f [ (sum_j x[row,j]*Wy[j,f]) * Wx[row%I,f] ] * Wz[k,f]
constexpr int kI = 2048;
constexpr int kJ = 1024;
constexpr int kK = 1024;
constexpr int kF = 32;
constexpr int kRows = 16 * 2048;        // 32768

// ---------------------------------------------------------------------------
// Stage 1: t[row,f] = (sum_j x[row,j]*Wy[j,f]) * Wx[row%I,f]
// Structural balance: 64 FLOP per x-float vs VALU/HBM balance of ~100 ->
// nearly compute-bound; needs ~65% FMA issue density AND deep prefetch.
//   - R=8 rows/thread: per 32-j window = 4 ds_read + 8 gl + 128 FMA (91% FMA)
//   - 256 thr/block + launch_bounds(256,2): VGPR cap 256; need ~160.
//     (Session law: VGPR_Count==cap => spill. (512,2)=128 cap killed R=8
//      in rounds 7/8; this is the first R=8 config that fits.)
//   - Triple-buffer x0/x1/x2, prefetch 2 windows ahead (~600+ cyc slack).
//     All buffer indices static (unrolled phase switch).
//   - Wy chunks of 256 j = 32 KB LDS -> 3 blocks/CU = 12 waves/CU.
// 1024 blocks x 256 thr; wave owns 8 rows; lane=(jo:8)x(fq:8);
// x loads: 8 consecutive 16B quads of one row per instr (coalesced, 8-way
// fq-broadcast). j-reduce = butterfly shfl_xor(8/16/32), lane jo = row jo.
// ---------------------------------------------------------------------------
constexpr int kCJ = 256;                // j per staged chunk

#define LOADW(buf, jabs)                                               \
    _Pragma("unroll")                                                  \
    for (int r = 0; r < 8; ++r)                                        \
        buf[r] = *reinterpret_cast<const float4*>(                     \
            xrow0 + (size_t)r * kJ + (jabs));

#define COMPW(buf, jl)                                                 \
    _Pragma("unroll")                                                  \
    for (int u = 0; u < 4; ++u) {                                      \
        const float4 wv = *reinterpret_cast<const float4*>(            \
            &wyb[(((jl) + jo * 4 + u) * 8 + fq) * 4]);                 \
        _Pragma("unroll")                                              \
        for (int r = 0; r < 8; ++r) {                                  \
            const float xs = (u == 0) ? buf[r].x : (u == 1) ? buf[r].y \
                           : (u == 2) ? buf[r].z : buf[r].w;           \
            acc[r].x = fmaf(xs, wv.x, acc[r].x);                       \
            acc[r].y = fmaf(xs, wv.y, acc[r].y);                       \
            acc[r].z = fmaf(xs, wv.z, acc[r].z);                       \
            acc[r].w = fmaf(xs, wv.w, acc[r].w);                       \
        }                                                              \
    }

// prefetch window gw+2 into bp, then compute window gw from bc
#define STEP(bc, bp, gw, wd)                                           \
    if ((gw) + 2 < 32) { LOADW(bp, ((gw) + 2) * 32) }                  \
    COMPW(bc, (wd) * 32)

__global__ __launch_bounds__(256, 2)
void ge_stage1(const float* __restrict__ x,
               const float* __restrict__ Wx,
               const float* __restrict__ Wy,
               float* __restrict__ t)
{
    __shared__ float wyb[kCJ * kF];     // 32 KiB, linear [j][f] quads

    const int tid  = threadIdx.x;
    const int lane = tid & 63;
    const int w    = tid >> 6;          // wave 0..3
    const int fq   = lane & 7;
    const int jo   = lane >> 3;         // 0..7
    const int rowBase = blockIdx.x * 32 + w * 8;

    const float* __restrict__ xrow0 = x + (size_t)rowBase * kJ + jo * 4;

    float4 acc[8];
#pragma unroll
    for (int r = 0; r < 8; ++r) acc[r] = make_float4(0.f, 0.f, 0.f, 0.f);

    float4 x0[8], x1[8], x2[8];
    LOADW(x0, 0)                        // window 0
    LOADW(x1, 32)                       // window 1

#pragma unroll
    for (int c = 0; c < 4; ++c) {
        __syncthreads();                // previous chunk's readers done
        {   // stage 256x32 floats = 2048 float4 / 256 thr = 8 each, linear
            const float4* src = reinterpret_cast<const float4*>(
                Wy + (size_t)c * kCJ * kF);
            float4* dst = reinterpret_cast<float4*>(wyb);
#pragma unroll
            for (int p = 0; p < 8; ++p)
                dst[tid + p * 256] = src[tid + p * 256];
        }
        __syncthreads();

#pragma unroll
        for (int wd = 0; wd < 8; ++wd) {
            const int gw = c * 8 + wd;            // compile-time constant
            const int ph = gw % 3;
            if (ph == 0)      { STEP(x0, x2, gw, wd) }
            else if (ph == 1) { STEP(x1, x0, gw, wd) }
            else              { STEP(x2, x1, gw, wd) }
        }
    }

    // butterfly reduce over jo lanes (bits 3..5); lane jo takes row jo
    float4 ov = make_float4(0.f, 0.f, 0.f, 0.f);
#pragma unroll
    for (int r = 0; r < 8; ++r) {
        float4 v = acc[r];
        v.x += __shfl_xor(v.x, 8);
        v.y += __shfl_xor(v.y, 8);
        v.z += __shfl_xor(v.z, 8);
        v.w += __shfl_xor(v.w, 8);
        v.x += __shfl_xor(v.x, 16);
        v.y += __shfl_xor(v.y, 16);
        v.z += __shfl_xor(v.z, 16);
        v.w += __shfl_xor(v.w, 16);
        v.x += __shfl_xor(v.x, 32);
        v.y += __shfl_xor(v.y, 32);
        v.z += __shfl_xor(v.z, 32);
        v.w += __shfl_xor(v.w, 32);
        if (jo == r) ov = v;            // static-unrolled predicated select
    }

    const int f0  = fq * 4;
    const int row = rowBase + jo;
    const int i   = row & (kI - 1);
    const float4 g = *reinterpret_cast<const float4*>(Wx + (size_t)i * kF + f0);
    ov.x *= g.x; ov.y *= g.y; ov.z *= g.z; ov.w *= g.w;
    *reinterpret_cast<float4*>(t + (size_t)row * kF + f0) = ov;
}

// ---------------------------------------------------------------------------
// Stage 2: out[row,k] = sum_f t[row,f] * Wz[k,f]   (~28 us measured, round 5)
// 512 blocks x 512 threads, 64 rows/block, thread owns 2 k-columns with Wz
// in 64 VGPRs. launch_bounds(512,2): the (512,4) variant spilled (round 4).
// ---------------------------------------------------------------------------
__global__ __launch_bounds__(512, 2)
void ge_stage2(const float* __restrict__ t,
               const float* __restrict__ Wz,
               float* __restrict__ out)
{
    __shared__ float t2[64][kF];                       // 8 KiB = 512 float4

    const int tid = threadIdx.x;
    const int rowBase = blockIdx.x * 64;

    reinterpret_cast<float4*>(&t2[0][0])[tid] =
        reinterpret_cast<const float4*>(t + (size_t)rowBase * kF)[tid];

    const int k0 = tid * 2;
    float4 wa[8], wb[8];
#pragma unroll
    for (int q = 0; q < 8; ++q) {
        wa[q] = *reinterpret_cast<const float4*>(Wz + (size_t)k0 * kF + q * 4);
        wb[q] = *reinterpret_cast<const float4*>(Wz + (size_t)(k0 + 1) * kF + q * 4);
    }
    __syncthreads();

    float* __restrict__ orow = out + (size_t)rowBase * kK + k0;

    for (int r = 0; r < 64; ++r) {
        float4 tr[8];
#pragma unroll
        for (int q = 0; q < 8; ++q)
            tr[q] = *reinterpret_cast<const float4*>(&t2[r][q * 4]);

        float a0 = 0.f, a1 = 0.f, b0 = 0.f, b1 = 0.f;
#pragma unroll
        for (int q = 0; q < 8; q += 2) {
            a0 = fmaf(tr[q].x, wa[q].x, a0);
            a0 = fmaf(tr[q].y, wa[q].y, a0);
            a0 = fmaf(tr[q].z, wa[q].z, a0);
            a0 = fmaf(tr[q].w, wa[q].w, a0);
            a1 = fmaf(tr[q + 1].x, wa[q + 1].x, a1);
            a1 = fmaf(tr[q + 1].y, wa[q + 1].y, a1);
            a1 = fmaf(tr[q + 1].z, wa[q + 1].z, a1);
            a1 = fmaf(tr[q + 1].w, wa[q + 1].w, a1);
            b0 = fmaf(tr[q].x, wb[q].x, b0);
            b0 = fmaf(tr[q].y, wb[q].y, b0);
            b0 = fmaf(tr[q].z, wb[q].z, b0);
            b0 = fmaf(tr[q].w, wb[q].w, b0);
            b1 = fmaf(tr[q + 1].x, wb[q + 1].x, b1);
            b1 = fmaf(tr[q + 1].y, wb[q + 1].y, b1);
            b1 = fmaf(tr[q + 1].z, wb[q + 1].z, b1);
            b1 = fmaf(tr[q + 1].w, wb[q + 1].w, b1);
        }
        float2 o;
        o.x = a0 + a1;
        o.y = b0 + b1;
        *reinterpret_cast<float2*>(orow + (size_t)r * kK) = o;
    }
}

// ---------------------------------------------------------------------------
// Fallback: round-1 fused kernel (proven correct) if ws too small.
// ---------------------------------------------------------------------------
__global__ __launch_bounds__(256, 2)
void gated_encoder_fused(const float* __restrict__ x,
                         const float* __restrict__ Wx,
                         const float* __restrict__ Wy,
                         const float* __restrict__ Wz,
                         float* __restrict__ out)
{
    __shared__ float t2[64][kF + 4];

    const int tid  = threadIdx.x;
    const int lane = tid & 63;
    const int wv   = tid >> 6;

    const int rloc = wv * 16 + (lane >> 2);
    const int row  = blockIdx.x * 64 + rloc;
    const int fg8  = (lane & 3) * 8;

    const float* __restrict__ xrow = x + (size_t)row * kJ;

    float acc[8];
#pragma unroll
    for (int u = 0; u < 8; ++u) acc[u] = 0.0f;

    for (int j = 0; j < kJ; j += 8) {
        const float4 xv0 = *reinterpret_cast<const float4*>(xrow + j);
        const float4 xv1 = *reinterpret_cast<const float4*>(xrow + j + 4);
        const float xs[8] = {xv0.x, xv0.y, xv0.z, xv0.w,
                             xv1.x, xv1.y, xv1.z, xv1.w};
#pragma unroll
        for (int u = 0; u < 8; ++u) {
            const float* wyp = Wy + (size_t)(j + u) * kF + fg8;
            const float4 w0 = *reinterpret_cast<const float4*>(wyp);
            const float4 w1 = *reinterpret_cast<const float4*>(wyp + 4);
            acc[0] = fmaf(xs[u], w0.x, acc[0]);
            acc[1] = fmaf(xs[u], w0.y, acc[1]);
            acc[2] = fmaf(xs[u], w0.z, acc[2]);
            acc[3] = fmaf(xs[u], w0.w, acc[3]);
            acc[4] = fmaf(xs[u], w1.x, acc[4]);
            acc[5] = fmaf(xs[u], w1.y, acc[5]);
            acc[6] = fmaf(xs[u], w1.z, acc[6]);
            acc[7] = fmaf(xs[u], w1.w, acc[7]);
        }
    }

    const int i = row & (kI - 1);
    const float* wxp = Wx + (size_t)i * kF + fg8;
    const float4 g0 = *reinterpret_cast<const float4*>(wxp);
    const float4 g1 = *reinterpret_cast<const float4*>(wxp + 4);
    float4 r0, r1;
    r0.x = acc[0] * g0.x;  r0.y = acc[1] * g0.y;
    r0.z = acc[2] * g0.z;  r0.w = acc[3] * g0.w;
    r1.x = acc[4] * g1.x;  r1.y = acc[5] * g1.y;
    r1.z = acc[6] * g1.z;  r1.w = acc[7] * g1.w;
    *reinterpret_cast<float4*>(&t2[rloc][fg8])     = r0;
    *reinterpret_cast<float4*>(&t2[rloc][fg8 + 4]) = r1;

    __syncthreads();

    const size_t outBase = (size_t)blockIdx.x * 64 * kK;

#pragma unroll
    for (int pass = 0; pass < 2; ++pass) {
        const int k1 = pass * 512 + tid;
        const int k2 = k1 + 256;
        const float* wz1 = Wz + (size_t)k1 * kF;
        const float* wz2 = Wz + (size_t)k2 * kF;
        float4 z1[8], z2[8];
#pragma unroll
        for (int m = 0; m < 8; ++m) {
            z1[m] = *reinterpret_cast<const float4*>(wz1 + 4 * m);
            z2[m] = *reinterpret_cast<const float4*>(wz2 + 4 * m);
        }
        for (int r = 0; r < 64; ++r) {
            float4 a1 = {0.f, 0.f, 0.f, 0.f};
            float4 a2 = {0.f, 0.f, 0.f, 0.f};
#pragma unroll
            for (int m = 0; m < 8; ++m) {
                const float4 tv = *reinterpret_cast<const float4*>(&t2[r][4 * m]);
                a1.x = fmaf(tv.x, z1[m].x, a1.x);
                a1.y = fmaf(tv.y, z1[m].y, a1.y);
                a1.z = fmaf(tv.z, z1[m].z, a1.z);
                a1.w = fmaf(tv.w, z1[m].w, a1.w);
                a2.x = fmaf(tv.x, z2[m].x, a2.x);
                a2.y = fmaf(tv.y, z2[m].y, a2.y);
                a2.z = fmaf(tv.z, z2[m].z, a2.z);
                a2.w = fmaf(tv.w, z2[m].w, a2.w);
            }
            out[outBase + (size_t)r * kK + k1] = (a1.x + a1.y) + (a1.z + a1.w);
            out[outBase + (size_t)r * kK + k2] = (a2.x + a2.y) + (a2.z + a2.w);
        }
    }
}

extern "C" void kernel_launch(void* const* d_in, const int* in_sizes, int n_in,
                              void* d_out, int out_size, void* d_ws, size_t ws_size,
                              hipStream_t stream) {
    const float* x  = (const float*)d_in[0];   // (B, I, J)
    const float* Wx = (const float*)d_in[1];   // (I, F)
    const float* Wy = (const float*)d_in[2];   // (J, F)
    const float* Wz = (const float*)d_in[3];   // (K, F)
    float* out = (float*)d_out;                // (B, I, K) f32

    const size_t tBytes = (size_t)kRows * kF * sizeof(float);   // 4 MiB

    if (ws_size >= tBytes && d_ws != nullptr) {
        float* t = (float*)d_ws;
        ge_stage1<<<dim3(kRows / 32), 256, 0, stream>>>(x, Wx, Wy, t);
        ge_stage2<<<dim3(kRows / 64), 512, 0, stream>>>(t, Wz, out);
    } else {
        gated_encoder_fused<<<dim3(kRows / 64), 256, 0, stream>>>(x, Wx, Wy, Wz, out);
    }
}

// Round 11
// 90.532 us; speedup vs baseline: 2.1303x; 1.1939x over previous
//
#include <hip/hip_runtime.h>
#include <hip/hip_bf16.h>
#include <string.h>

// GatedEncoderLayer: B=16, I=2048, J=1024, K=1024, F=32
// out[row,k] = sum_f [ (sum_j x[row,j]*Wy[j,f]) * Wx[row%I,f] ] * Wz[k,f]
constexpr int kI = 2048;
constexpr int kJ = 1024;
constexpr int kK = 1024;
constexpr int kF = 32;
constexpr int kRows = 16 * 2048;        // 32768

typedef __attribute__((ext_vector_type(8))) short short8v;
typedef __attribute__((ext_vector_type(4))) float f32x4;

__device__ inline unsigned short bf16_hi_bits(float v) {
    __hip_bfloat16 h = __float2bfloat16(v);      // RNE on gfx950
    unsigned short s;
    memcpy(&s, &h, 2);
    return s;
}
__device__ inline float bf16_bits_to_f(unsigned short s) {
    unsigned u = (unsigned)s << 16;
    float f;
    memcpy(&f, &u, 4);
    return f;
}
__device__ inline short8v as_s8(uint4 u) {
    union { uint4 a; short8v b; } c;
    c.a = u;
    return c.b;
}

// ---------------------------------------------------------------------------
// Prepack: Wy[1024][32] f32 -> fragment-ready packed bf16 hi/lo in d_ws.
// Entry e = ((ks*2 + ftile)*2 + h)*64 + lane ; 16 B each; 8192 entries=128 KB.
// Element p of entry: bf16x2( Wy[ks*32+(lane>>4)*8+2p][f], ...[2p+1][f] ),
// f = (lane&15)+ftile*16; h=0 hi, h=1 lo.  Same (group,elem)->j map as the
// x-fragment loader => contraction correct for ANY internal HW k-order.
// ---------------------------------------------------------------------------
__global__ __launch_bounds__(256)
void ge_prepack(const float* __restrict__ Wy, uint4* __restrict__ wyp)
{
    const int e  = blockIdx.x * 256 + threadIdx.x;   // 0..8191
    const int l  = e & 63;
    const int h  = (e >> 6) & 1;
    const int tf = (e >> 7) & 1;
    const int ks = e >> 8;
    const int f  = (l & 15) + tf * 16;
    const int j0 = ks * 32 + (l >> 4) * 8;

    unsigned d[4];
#pragma unroll
    for (int p = 0; p < 4; ++p) {
        const float v0 = Wy[(size_t)(j0 + 2 * p) * kF + f];
        const float v1 = Wy[(size_t)(j0 + 2 * p + 1) * kF + f];
        unsigned short s0, s1;
        if (h == 0) {
            s0 = bf16_hi_bits(v0);
            s1 = bf16_hi_bits(v1);
        } else {
            s0 = bf16_hi_bits(v0 - bf16_bits_to_f(bf16_hi_bits(v0)));
            s1 = bf16_hi_bits(v1 - bf16_bits_to_f(bf16_hi_bits(v1)));
        }
        d[p] = (unsigned)s0 | ((unsigned)s1 << 16);
    }
    wyp[e] = make_uint4(d[0], d[1], d[2], d[3]);
}

// ---------------------------------------------------------------------------
// Stage 1 (MFMA): t[row,f] = (sum_j x[row,j]*Wy[j,f]) * Wx[row%I,f]
// bf16-split: x*w ~= xh*wh + xh*wl + xl*wh (drop xl*wl ~2^-18 rel; worst-case
// sum ~1e-4 << 1.35e-3 threshold). mfma_f32_16x16x32_bf16, f32 accum.
// Wave = 16 rows x 32 f: 2 n-tiles, 32 K-steps, 6 MFMA/K-step = 192 MFMA.
// A (x): lane reads x[rowBase+(lane&15)][ks*32+(lane>>4)*8 + 0..7] f32 -> cvt.
//   Per K-step the e-pair covers 128 contiguous B/row; MSHR-merged; x read
//   exactly once (21 us HBM floor).
// B (Wy): 4 coalesced 1KB uint4 loads/K-step from packed wyp (L2-resident).
// NO LDS, NO barriers; ~70 VGPR -> ~7 waves/SIMD; pure streaming.
// D layout (verified m89): n=lane&15, m=(lane>>4)*4+reg.
// ---------------------------------------------------------------------------
__global__ __launch_bounds__(256, 2)
void ge_stage1_mfma(const float* __restrict__ x,
                    const float* __restrict__ Wx,
                    const uint4* __restrict__ wyp,
                    float* __restrict__ t)
{
    const int tid  = threadIdx.x;
    const int lane = tid & 63;
    const int wv   = tid >> 6;
    const int rowBase = blockIdx.x * 64 + wv * 16;
    const int mrow = lane & 15;
    const int g    = lane >> 4;

    const float* __restrict__ xp = x + (size_t)(rowBase + mrow) * kJ + g * 8;
    const uint4* __restrict__ bp = wyp + lane;

    f32x4 c0 = {0.f, 0.f, 0.f, 0.f};
    f32x4 c1 = {0.f, 0.f, 0.f, 0.f};

#pragma unroll 2
    for (int ks = 0; ks < 32; ++ks) {
        // B fragments: ((ks*2+tf)*2+h)*64 lanes-contiguous
        const uint4 b0h = bp[(size_t)(ks * 4 + 0) * 64];
        const uint4 b0l = bp[(size_t)(ks * 4 + 1) * 64];
        const uint4 b1h = bp[(size_t)(ks * 4 + 2) * 64];
        const uint4 b1l = bp[(size_t)(ks * 4 + 3) * 64];

        // A fragment: 8 consecutive f32 of my row
        const float4 xa = *reinterpret_cast<const float4*>(xp + ks * 32);
        const float4 xb = *reinterpret_cast<const float4*>(xp + ks * 32 + 4);
        const float xv[8] = {xa.x, xa.y, xa.z, xa.w, xb.x, xb.y, xb.z, xb.w};

        short8v ah, al;
#pragma unroll
        for (int e = 0; e < 8; ++e) {
            const unsigned short hb = bf16_hi_bits(xv[e]);
            const float hf = bf16_bits_to_f(hb);
            const unsigned short lb = bf16_hi_bits(xv[e] - hf);
            ah[e] = (short)hb;
            al[e] = (short)lb;
        }

        c0 = __builtin_amdgcn_mfma_f32_16x16x32_bf16(ah, as_s8(b0h), c0, 0, 0, 0);
        c1 = __builtin_amdgcn_mfma_f32_16x16x32_bf16(ah, as_s8(b1h), c1, 0, 0, 0);
        c0 = __builtin_amdgcn_mfma_f32_16x16x32_bf16(ah, as_s8(b0l), c0, 0, 0, 0);
        c1 = __builtin_amdgcn_mfma_f32_16x16x32_bf16(ah, as_s8(b1l), c1, 0, 0, 0);
        c0 = __builtin_amdgcn_mfma_f32_16x16x32_bf16(al, as_s8(b0h), c0, 0, 0, 0);
        c1 = __builtin_amdgcn_mfma_f32_16x16x32_bf16(al, as_s8(b1h), c1, 0, 0, 0);
    }

    // epilogue: gate by Wx, store. D: n=lane&15, m=(lane>>4)*4+reg.
    const int n = lane & 15;
#pragma unroll
    for (int r = 0; r < 4; ++r) {
        const int row = rowBase + g * 4 + r;
        const int i   = row & (kI - 1);
        t[(size_t)row * kF + n]      = c0[r] * Wx[(size_t)i * kF + n];
        t[(size_t)row * kF + 16 + n] = c1[r] * Wx[(size_t)i * kF + 16 + n];
    }
}

// ---------------------------------------------------------------------------
// Stage 1 (VALU fallback, ~83 us): round-10 version, used if ws lacks wyp room.
// ---------------------------------------------------------------------------
constexpr int kCJ = 256;

#define LOADW(buf, jabs)                                               \
    _Pragma("unroll")                                                  \
    for (int r = 0; r < 8; ++r)                                        \
        buf[r] = *reinterpret_cast<const float4*>(                     \
            xrow0 + (size_t)r * kJ + (jabs));

#define COMPW(buf, jl)                                                 \
    _Pragma("unroll")                                                  \
    for (int u = 0; u < 4; ++u) {                                      \
        const float4 wv = *reinterpret_cast<const float4*>(            \
            &wyb[(((jl) + jo * 4 + u) * 8 + fq) * 4]);                 \
        _Pragma("unroll")                                              \
        for (int r = 0; r < 8; ++r) {                                  \
            const float xs = (u == 0) ? buf[r].x : (u == 1) ? buf[r].y \
                           : (u == 2) ? buf[r].z : buf[r].w;           \
            acc[r].x = fmaf(xs, wv.x, acc[r].x);                       \
            acc[r].y = fmaf(xs, wv.y, acc[r].y);                       \
            acc[r].z = fmaf(xs, wv.z, acc[r].z);                       \
            acc[r].w = fmaf(xs, wv.w, acc[r].w);                       \
        }                                                              \
    }

#define STEP(bc, bp, gw, wd)                                           \
    if ((gw) + 2 < 32) { LOADW(bp, ((gw) + 2) * 32) }                  \
    COMPW(bc, (wd) * 32)

__global__ __launch_bounds__(256, 2)
void ge_stage1_valu(const float* __restrict__ x,
                    const float* __restrict__ Wx,
                    const float* __restrict__ Wy,
                    float* __restrict__ t)
{
    __shared__ float wyb[kCJ * kF];

    const int tid  = threadIdx.x;
    const int lane = tid & 63;
    const int w    = tid >> 6;
    const int fq   = lane & 7;
    const int jo   = lane >> 3;
    const int rowBase = blockIdx.x * 32 + w * 8;

    const float* __restrict__ xrow0 = x + (size_t)rowBase * kJ + jo * 4;

    float4 acc[8];
#pragma unroll
    for (int r = 0; r < 8; ++r) acc[r] = make_float4(0.f, 0.f, 0.f, 0.f);

    float4 x0[8], x1[8], x2[8];
    LOADW(x0, 0)
    LOADW(x1, 32)

#pragma unroll
    for (int c = 0; c < 4; ++c) {
        __syncthreads();
        {
            const float4* src = reinterpret_cast<const float4*>(
                Wy + (size_t)c * kCJ * kF);
            float4* dst = reinterpret_cast<float4*>(wyb);
#pragma unroll
            for (int p = 0; p < 8; ++p)
                dst[tid + p * 256] = src[tid + p * 256];
        }
        __syncthreads();

#pragma unroll
        for (int wd = 0; wd < 8; ++wd) {
            const int gw = c * 8 + wd;
            const int ph = gw % 3;
            if (ph == 0)      { STEP(x0, x2, gw, wd) }
            else if (ph == 1) { STEP(x1, x0, gw, wd) }
            else              { STEP(x2, x1, gw, wd) }
        }
    }

    float4 ov = make_float4(0.f, 0.f, 0.f, 0.f);
#pragma unroll
    for (int r = 0; r < 8; ++r) {
        float4 v = acc[r];
        v.x += __shfl_xor(v.x, 8);  v.y += __shfl_xor(v.y, 8);
        v.z += __shfl_xor(v.z, 8);  v.w += __shfl_xor(v.w, 8);
        v.x += __shfl_xor(v.x, 16); v.y += __shfl_xor(v.y, 16);
        v.z += __shfl_xor(v.z, 16); v.w += __shfl_xor(v.w, 16);
        v.x += __shfl_xor(v.x, 32); v.y += __shfl_xor(v.y, 32);
        v.z += __shfl_xor(v.z, 32); v.w += __shfl_xor(v.w, 32);
        if (jo == r) ov = v;
    }

    const int f0  = fq * 4;
    const int row = rowBase + jo;
    const int i   = row & (kI - 1);
    const float4 g = *reinterpret_cast<const float4*>(Wx + (size_t)i * kF + f0);
    ov.x *= g.x; ov.y *= g.y; ov.z *= g.z; ov.w *= g.w;
    *reinterpret_cast<float4*>(t + (size_t)row * kF + f0) = ov;
}

// ---------------------------------------------------------------------------
// Stage 2: out[row,k] = sum_f t[row,f] * Wz[k,f]   (~28 us measured, round 5)
// ---------------------------------------------------------------------------
__global__ __launch_bounds__(512, 2)
void ge_stage2(const float* __restrict__ t,
               const float* __restrict__ Wz,
               float* __restrict__ out)
{
    __shared__ float t2[64][kF];

    const int tid = threadIdx.x;
    const int rowBase = blockIdx.x * 64;

    reinterpret_cast<float4*>(&t2[0][0])[tid] =
        reinterpret_cast<const float4*>(t + (size_t)rowBase * kF)[tid];

    const int k0 = tid * 2;
    float4 wa[8], wb[8];
#pragma unroll
    for (int q = 0; q < 8; ++q) {
        wa[q] = *reinterpret_cast<const float4*>(Wz + (size_t)k0 * kF + q * 4);
        wb[q] = *reinterpret_cast<const float4*>(Wz + (size_t)(k0 + 1) * kF + q * 4);
    }
    __syncthreads();

    float* __restrict__ orow = out + (size_t)rowBase * kK + k0;

    for (int r = 0; r < 64; ++r) {
        float4 tr[8];
#pragma unroll
        for (int q = 0; q < 8; ++q)
            tr[q] = *reinterpret_cast<const float4*>(&t2[r][q * 4]);

        float a0 = 0.f, a1 = 0.f, b0 = 0.f, b1 = 0.f;
#pragma unroll
        for (int q = 0; q < 8; q += 2) {
            a0 = fmaf(tr[q].x, wa[q].x, a0);
            a0 = fmaf(tr[q].y, wa[q].y, a0);
            a0 = fmaf(tr[q].z, wa[q].z, a0);
            a0 = fmaf(tr[q].w, wa[q].w, a0);
            a1 = fmaf(tr[q + 1].x, wa[q + 1].x, a1);
            a1 = fmaf(tr[q + 1].y, wa[q + 1].y, a1);
            a1 = fmaf(tr[q + 1].z, wa[q + 1].z, a1);
            a1 = fmaf(tr[q + 1].w, wa[q + 1].w, a1);
            b0 = fmaf(tr[q].x, wb[q].x, b0);
            b0 = fmaf(tr[q].y, wb[q].y, b0);
            b0 = fmaf(tr[q].z, wb[q].z, b0);
            b0 = fmaf(tr[q].w, wb[q].w, b0);
            b1 = fmaf(tr[q + 1].x, wb[q + 1].x, b1);
            b1 = fmaf(tr[q + 1].y, wb[q + 1].y, b1);
            b1 = fmaf(tr[q + 1].z, wb[q + 1].z, b1);
            b1 = fmaf(tr[q + 1].w, wb[q + 1].w, b1);
        }
        float2 o;
        o.x = a0 + a1;
        o.y = b0 + b1;
        *reinterpret_cast<float2*>(orow + (size_t)r * kK) = o;
    }
}

// ---------------------------------------------------------------------------
// Fallback: round-1 fused kernel (proven correct) if ws too small.
// ---------------------------------------------------------------------------
__global__ __launch_bounds__(256, 2)
void gated_encoder_fused(const float* __restrict__ x,
                         const float* __restrict__ Wx,
                         const float* __restrict__ Wy,
                         const float* __restrict__ Wz,
                         float* __restrict__ out)
{
    __shared__ float t2[64][kF + 4];

    const int tid  = threadIdx.x;
    const int lane = tid & 63;
    const int wv   = tid >> 6;

    const int rloc = wv * 16 + (lane >> 2);
    const int row  = blockIdx.x * 64 + rloc;
    const int fg8  = (lane & 3) * 8;

    const float* __restrict__ xrow = x + (size_t)row * kJ;

    float acc[8];
#pragma unroll
    for (int u = 0; u < 8; ++u) acc[u] = 0.0f;

    for (int j = 0; j < kJ; j += 8) {
        const float4 xv0 = *reinterpret_cast<const float4*>(xrow + j);
        const float4 xv1 = *reinterpret_cast<const float4*>(xrow + j + 4);
        const float xs[8] = {xv0.x, xv0.y, xv0.z, xv0.w,
                             xv1.x, xv1.y, xv1.z, xv1.w};
#pragma unroll
        for (int u = 0; u < 8; ++u) {
            const float* wyp = Wy + (size_t)(j + u) * kF + fg8;
            const float4 w0 = *reinterpret_cast<const float4*>(wyp);
            const float4 w1 = *reinterpret_cast<const float4*>(wyp + 4);
            acc[0] = fmaf(xs[u], w0.x, acc[0]);
            acc[1] = fmaf(xs[u], w0.y, acc[1]);
            acc[2] = fmaf(xs[u], w0.z, acc[2]);
            acc[3] = fmaf(xs[u], w0.w, acc[3]);
            acc[4] = fmaf(xs[u], w1.x, acc[4]);
            acc[5] = fmaf(xs[u], w1.y, acc[5]);
            acc[6] = fmaf(xs[u], w1.z, acc[6]);
            acc[7] = fmaf(xs[u], w1.w, acc[7]);
        }
    }

    const int i = row & (kI - 1);
    const float* wxp = Wx + (size_t)i * kF + fg8;
    const float4 g0 = *reinterpret_cast<const float4*>(wxp);
    const float4 g1 = *reinterpret_cast<const float4*>(wxp + 4);
    float4 r0, r1;
    r0.x = acc[0] * g0.x;  r0.y = acc[1] * g0.y;
    r0.z = acc[2] * g0.z;  r0.w = acc[3] * g0.w;
    r1.x = acc[4] * g1.x;  r1.y = acc[5] * g1.y;
    r1.z = acc[6] * g1.z;  r1.w = acc[7] * g1.w;
    *reinterpret_cast<float4*>(&t2[rloc][fg8])     = r0;
    *reinterpret_cast<float4*>(&t2[rloc][fg8 + 4]) = r1;

    __syncthreads();

    const size_t outBase = (size_t)blockIdx.x * 64 * kK;

#pragma unroll
    for (int pass = 0; pass < 2; ++pass) {
        const int k1 = pass * 512 + tid;
        const int k2 = k1 + 256;
        const float* wz1 = Wz + (size_t)k1 * kF;
        const float* wz2 = Wz + (size_t)k2 * kF;
        float4 z1[8], z2[8];
#pragma unroll
        for (int m = 0; m < 8; ++m) {
            z1[m] = *reinterpret_cast<const float4*>(wz1 + 4 * m);
            z2[m] = *reinterpret_cast<const float4*>(wz2 + 4 * m);
        }
        for (int r = 0; r < 64; ++r) {
            float4 a1 = {0.f, 0.f, 0.f, 0.f};
            float4 a2 = {0.f, 0.f, 0.f, 0.f};
#pragma unroll
            for (int m = 0; m < 8; ++m) {
                const float4 tv = *reinterpret_cast<const float4*>(&t2[r][4 * m]);
                a1.x = fmaf(tv.x, z1[m].x, a1.x);
                a1.y = fmaf(tv.y, z1[m].y, a1.y);
                a1.z = fmaf(tv.z, z1[m].z, a1.z);
                a1.w = fmaf(tv.w, z1[m].w, a1.w);
                a2.x = fmaf(tv.x, z2[m].x, a2.x);
                a2.y = fmaf(tv.y, z2[m].y, a2.y);
                a2.z = fmaf(tv.z, z2[m].z, a2.z);
                a2.w = fmaf(tv.w, z2[m].w, a2.w);
            }
            out[outBase + (size_t)r * kK + k1] = (a1.x + a1.y) + (a1.z + a1.w);
            out[outBase + (size_t)r * kK + k2] = (a2.x + a2.y) + (a2.z + a2.w);
        }
    }
}

extern "C" void kernel_launch(void* const* d_in, const int* in_sizes, int n_in,
                              void* d_out, int out_size, void* d_ws, size_t ws_size,
                              hipStream_t stream) {
    const float* x  = (const float*)d_in[0];   // (B, I, J)
    const float* Wx = (const float*)d_in[1];   // (I, F)
    const float* Wy = (const float*)d_in[2];   // (J, F)
    const float* Wz = (const float*)d_in[3];   // (K, F)
    float* out = (float*)d_out;                // (B, I, K) f32

    const size_t tBytes  = (size_t)kRows * kF * sizeof(float);   // 4 MiB
    const size_t wyBytes = 8192 * sizeof(uint4);                 // 128 KiB

    if (ws_size >= tBytes + wyBytes && d_ws != nullptr) {
        float* t   = (float*)d_ws;
        uint4* wyp = (uint4*)((char*)d_ws + tBytes);
        ge_prepack<<<dim3(32), 256, 0, stream>>>(Wy, wyp);
        ge_stage1_mfma<<<dim3(kRows / 64), 256, 0, stream>>>(x, Wx, wyp, t);
        ge_stage2<<<dim3(kRows / 64), 512, 0, stream>>>(t, Wz, out);
    } else if (ws_size >= tBytes && d_ws != nullptr) {
        float* t = (float*)d_ws;
        ge_stage1_valu<<<dim3(kRows / 32), 256, 0, stream>>>(x, Wx, Wy, t);
        ge_stage2<<<dim3(kRows / 64), 512, 0, stream>>>(t, Wz, out);
    } else {
        gated_encoder_fused<<<dim3(kRows / 64), 256, 0, stream>>>(x, Wx, Wy, Wz, out);
    }
}

// Round 12
// 89.527 us; speedup vs baseline: 2.1542x; 1.0112x over previous
//
#include <hip/hip_runtime.h>
#include <hip/hip_bf16.h>
#include <string.h>

// GatedEncoderLayer: B=16, I=2048, J=1024, K=1024, F=32
// out[row,k] = sum_f [ (sum_j x[row,j]*Wy[j,f]) * Wx[row%I,f] ] * Wz[k,f]
constexpr int kI = 2048;
constexpr int kJ = 1024;
constexpr int kK = 1024;
constexpr int kF = 32;
constexpr int kRows = 16 * 2048;        // 32768

typedef __attribute__((ext_vector_type(8))) short short8v;
typedef __attribute__((ext_vector_type(4))) float f32x4;

__device__ inline unsigned short bf16_hi_bits(float v) {
    __hip_bfloat16 h = __float2bfloat16(v);      // RNE on gfx950
    unsigned short s;
    memcpy(&s, &h, 2);
    return s;
}
__device__ inline float bf16_bits_to_f(unsigned short s) {
    unsigned u = (unsigned)s << 16;
    float f;
    memcpy(&f, &u, 4);
    return f;
}
__device__ inline short8v as_s8(uint4 u) {
    union { uint4 a; short8v b; } c;
    c.a = u;
    return c.b;
}

// ---------------------------------------------------------------------------
// Prepack: Wy[1024][32] f32 -> fragment-ready packed bf16 hi/lo in d_ws.
// Entry e = ((ks*2 + ftile)*2 + h)*64 + lane ; 16 B each; 8192 entries=128 KB.
// Element p: bf16x2( Wy[ks*32+(lane>>4)*8+2p][f], ...[2p+1][f] ),
// f=(lane&15)+ftile*16; h=0 hi, h=1 lo. Same (group,elem)->j map as the
// x-fragment loader => contraction correct for ANY internal HW k-order.
// ---------------------------------------------------------------------------
__global__ __launch_bounds__(256)
void ge_prepack(const float* __restrict__ Wy, uint4* __restrict__ wyp)
{
    const int e  = blockIdx.x * 256 + threadIdx.x;   // 0..8191
    const int l  = e & 63;
    const int h  = (e >> 6) & 1;
    const int tf = (e >> 7) & 1;
    const int ks = e >> 8;
    const int f  = (l & 15) + tf * 16;
    const int j0 = ks * 32 + (l >> 4) * 8;

    unsigned d[4];
#pragma unroll
    for (int p = 0; p < 4; ++p) {
        const float v0 = Wy[(size_t)(j0 + 2 * p) * kF + f];
        const float v1 = Wy[(size_t)(j0 + 2 * p + 1) * kF + f];
        unsigned short s0, s1;
        if (h == 0) {
            s0 = bf16_hi_bits(v0);
            s1 = bf16_hi_bits(v1);
        } else {
            s0 = bf16_hi_bits(v0 - bf16_bits_to_f(bf16_hi_bits(v0)));
            s1 = bf16_hi_bits(v1 - bf16_bits_to_f(bf16_hi_bits(v1)));
        }
        d[p] = (unsigned)s0 | ((unsigned)s1 << 16);
    }
    wyp[e] = make_uint4(d[0], d[1], d[2], d[3]);
}

// ---------------------------------------------------------------------------
// Stage 1 (MFMA, j-split): t[row,f] = (sum_j x[row,j]*Wy[j,f]) * Wx[row%I,f]
// bf16-split: x*w ~= xh*wh + xh*wl + xl*wh (xl*wl dropped, ~2^-18 rel).
// Round-11 was latency-capped at 2 waves/SIMD (2048 waves, M=16 granularity).
// Fix: j-split x2 -> block = 4 waves = (rg:2)x(jh:2); each wave 16 rows x
// 512 j (16 K-steps). 1024 blocks, 4096 waves, launch_bounds(256,4)
// -> 4 blocks/CU = 4 waves/SIMD (VGPR cap 128, need ~110).
// j-halves combined via padded LDS (stride 9 -> bijective banks).
// Per K-step: 4 coalesced 1KB B-loads (L2) + 2 float4 x-loads + cvt + 6 MFMA.
// D layout (verified m89): n=lane&15, m=(lane>>4)*4+reg.
// ---------------------------------------------------------------------------
__global__ __launch_bounds__(256, 4)
void ge_stage1_mfma(const float* __restrict__ x,
                    const float* __restrict__ Wx,
                    const uint4* __restrict__ wyp,
                    float* __restrict__ t)
{
    __shared__ float red[2][64][9];     // 4.6 KB, stride-9 padded

    const int tid  = threadIdx.x;
    const int lane = tid & 63;
    const int wv   = tid >> 6;          // 0..3
    const int rg   = wv & 1;            // row-group
    const int jh   = wv >> 1;           // j-half
    const int rowBase = blockIdx.x * 32 + rg * 16;
    const int mrow = lane & 15;
    const int g    = lane >> 4;

    const float* __restrict__ xp =
        x + (size_t)(rowBase + mrow) * kJ + jh * 512 + g * 8;
    const uint4* __restrict__ bp = wyp + (size_t)jh * 16 * 4 * 64 + lane;

    f32x4 c0 = {0.f, 0.f, 0.f, 0.f};
    f32x4 c1 = {0.f, 0.f, 0.f, 0.f};

#pragma unroll 2
    for (int ks = 0; ks < 16; ++ks) {
        const uint4 b0h = bp[(size_t)(ks * 4 + 0) * 64];
        const uint4 b0l = bp[(size_t)(ks * 4 + 1) * 64];
        const uint4 b1h = bp[(size_t)(ks * 4 + 2) * 64];
        const uint4 b1l = bp[(size_t)(ks * 4 + 3) * 64];

        const float4 xa = *reinterpret_cast<const float4*>(xp + ks * 32);
        const float4 xb = *reinterpret_cast<const float4*>(xp + ks * 32 + 4);
        const float xv[8] = {xa.x, xa.y, xa.z, xa.w, xb.x, xb.y, xb.z, xb.w};

        short8v ah, al;
#pragma unroll
        for (int e = 0; e < 8; ++e) {
            const unsigned short hb = bf16_hi_bits(xv[e]);
            const float hf = bf16_bits_to_f(hb);
            const unsigned short lb = bf16_hi_bits(xv[e] - hf);
            ah[e] = (short)hb;
            al[e] = (short)lb;
        }

        c0 = __builtin_amdgcn_mfma_f32_16x16x32_bf16(ah, as_s8(b0h), c0, 0, 0, 0);
        c1 = __builtin_amdgcn_mfma_f32_16x16x32_bf16(ah, as_s8(b1h), c1, 0, 0, 0);
        c0 = __builtin_amdgcn_mfma_f32_16x16x32_bf16(ah, as_s8(b0l), c0, 0, 0, 0);
        c1 = __builtin_amdgcn_mfma_f32_16x16x32_bf16(ah, as_s8(b1l), c1, 0, 0, 0);
        c0 = __builtin_amdgcn_mfma_f32_16x16x32_bf16(al, as_s8(b0h), c0, 0, 0, 0);
        c1 = __builtin_amdgcn_mfma_f32_16x16x32_bf16(al, as_s8(b1h), c1, 0, 0, 0);
    }

    // combine j-halves: jh=1 publishes, jh=0 finishes + epilogue
    if (jh == 1) {
        float* rp = &red[rg][lane][0];
        rp[0] = c0[0]; rp[1] = c0[1]; rp[2] = c0[2]; rp[3] = c0[3];
        rp[4] = c1[0]; rp[5] = c1[1]; rp[6] = c1[2]; rp[7] = c1[3];
    }
    __syncthreads();
    if (jh == 0) {
        const float* rp = &red[rg][lane][0];
        c0[0] += rp[0]; c0[1] += rp[1]; c0[2] += rp[2]; c0[3] += rp[3];
        c1[0] += rp[4]; c1[1] += rp[5]; c1[2] += rp[6]; c1[3] += rp[7];

        const int n = lane & 15;
#pragma unroll
        for (int r = 0; r < 4; ++r) {
            const int row = rowBase + g * 4 + r;
            const int i   = row & (kI - 1);
            t[(size_t)row * kF + n]      = c0[r] * Wx[(size_t)i * kF + n];
            t[(size_t)row * kF + 16 + n] = c1[r] * Wx[(size_t)i * kF + 16 + n];
        }
    }
}

// ---------------------------------------------------------------------------
// Stage 1 (VALU fallback, ~83 us): used if ws lacks wyp room.
// ---------------------------------------------------------------------------
constexpr int kCJ = 256;

#define LOADW(buf, jabs)                                               \
    _Pragma("unroll")                                                  \
    for (int r = 0; r < 8; ++r)                                        \
        buf[r] = *reinterpret_cast<const float4*>(                     \
            xrow0 + (size_t)r * kJ + (jabs));

#define COMPW(buf, jl)                                                 \
    _Pragma("unroll")                                                  \
    for (int u = 0; u < 4; ++u) {                                      \
        const float4 wv = *reinterpret_cast<const float4*>(            \
            &wyb[(((jl) + jo * 4 + u) * 8 + fq) * 4]);                 \
        _Pragma("unroll")                                              \
        for (int r = 0; r < 8; ++r) {                                  \
            const float xs = (u == 0) ? buf[r].x : (u == 1) ? buf[r].y \
                           : (u == 2) ? buf[r].z : buf[r].w;           \
            acc[r].x = fmaf(xs, wv.x, acc[r].x);                       \
            acc[r].y = fmaf(xs, wv.y, acc[r].y);                       \
            acc[r].z = fmaf(xs, wv.z, acc[r].z);                       \
            acc[r].w = fmaf(xs, wv.w, acc[r].w);                       \
        }                                                              \
    }

#define STEP(bc, bp, gw, wd)                                           \
    if ((gw) + 2 < 32) { LOADW(bp, ((gw) + 2) * 32) }                  \
    COMPW(bc, (wd) * 32)

__global__ __launch_bounds__(256, 2)
void ge_stage1_valu(const float* __restrict__ x,
                    const float* __restrict__ Wx,
                    const float* __restrict__ Wy,
                    float* __restrict__ t)
{
    __shared__ float wyb[kCJ * kF];

    const int tid  = threadIdx.x;
    const int lane = tid & 63;
    const int w    = tid >> 6;
    const int fq   = lane & 7;
    const int jo   = lane >> 3;
    const int rowBase = blockIdx.x * 32 + w * 8;

    const float* __restrict__ xrow0 = x + (size_t)rowBase * kJ + jo * 4;

    float4 acc[8];
#pragma unroll
    for (int r = 0; r < 8; ++r) acc[r] = make_float4(0.f, 0.f, 0.f, 0.f);

    float4 x0[8], x1[8], x2[8];
    LOADW(x0, 0)
    LOADW(x1, 32)

#pragma unroll
    for (int c = 0; c < 4; ++c) {
        __syncthreads();
        {
            const float4* src = reinterpret_cast<const float4*>(
                Wy + (size_t)c * kCJ * kF);
            float4* dst = reinterpret_cast<float4*>(wyb);
#pragma unroll
            for (int p = 0; p < 8; ++p)
                dst[tid + p * 256] = src[tid + p * 256];
        }
        __syncthreads();

#pragma unroll
        for (int wd = 0; wd < 8; ++wd) {
            const int gw = c * 8 + wd;
            const int ph = gw % 3;
            if (ph == 0)      { STEP(x0, x2, gw, wd) }
            else if (ph == 1) { STEP(x1, x0, gw, wd) }
            else              { STEP(x2, x1, gw, wd) }
        }
    }

    float4 ov = make_float4(0.f, 0.f, 0.f, 0.f);
#pragma unroll
    for (int r = 0; r < 8; ++r) {
        float4 v = acc[r];
        v.x += __shfl_xor(v.x, 8);  v.y += __shfl_xor(v.y, 8);
        v.z += __shfl_xor(v.z, 8);  v.w += __shfl_xor(v.w, 8);
        v.x += __shfl_xor(v.x, 16); v.y += __shfl_xor(v.y, 16);
        v.z += __shfl_xor(v.z, 16); v.w += __shfl_xor(v.w, 16);
        v.x += __shfl_xor(v.x, 32); v.y += __shfl_xor(v.y, 32);
        v.z += __shfl_xor(v.z, 32); v.w += __shfl_xor(v.w, 32);
        if (jo == r) ov = v;
    }

    const int f0  = fq * 4;
    const int row = rowBase + jo;
    const int i   = row & (kI - 1);
    const float4 g = *reinterpret_cast<const float4*>(Wx + (size_t)i * kF + f0);
    ov.x *= g.x; ov.y *= g.y; ov.z *= g.z; ov.w *= g.w;
    *reinterpret_cast<float4*>(t + (size_t)row * kF + f0) = ov;
}

// ---------------------------------------------------------------------------
// Stage 2: out[row,k] = sum_f t[row,f] * Wz[k,f]   (~28 us measured, round 5)
// ---------------------------------------------------------------------------
__global__ __launch_bounds__(512, 2)
void ge_stage2(const float* __restrict__ t,
               const float* __restrict__ Wz,
               float* __restrict__ out)
{
    __shared__ float t2[64][kF];

    const int tid = threadIdx.x;
    const int rowBase = blockIdx.x * 64;

    reinterpret_cast<float4*>(&t2[0][0])[tid] =
        reinterpret_cast<const float4*>(t + (size_t)rowBase * kF)[tid];

    const int k0 = tid * 2;
    float4 wa[8], wb[8];
#pragma unroll
    for (int q = 0; q < 8; ++q) {
        wa[q] = *reinterpret_cast<const float4*>(Wz + (size_t)k0 * kF + q * 4);
        wb[q] = *reinterpret_cast<const float4*>(Wz + (size_t)(k0 + 1) * kF + q * 4);
    }
    __syncthreads();

    float* __restrict__ orow = out + (size_t)rowBase * kK + k0;

    for (int r = 0; r < 64; ++r) {
        float4 tr[8];
#pragma unroll
        for (int q = 0; q < 8; ++q)
            tr[q] = *reinterpret_cast<const float4*>(&t2[r][q * 4]);

        float a0 = 0.f, a1 = 0.f, b0 = 0.f, b1 = 0.f;
#pragma unroll
        for (int q = 0; q < 8; q += 2) {
            a0 = fmaf(tr[q].x, wa[q].x, a0);
            a0 = fmaf(tr[q].y, wa[q].y, a0);
            a0 = fmaf(tr[q].z, wa[q].z, a0);
            a0 = fmaf(tr[q].w, wa[q].w, a0);
            a1 = fmaf(tr[q + 1].x, wa[q + 1].x, a1);
            a1 = fmaf(tr[q + 1].y, wa[q + 1].y, a1);
            a1 = fmaf(tr[q + 1].z, wa[q + 1].z, a1);
            a1 = fmaf(tr[q + 1].w, wa[q + 1].w, a1);
            b0 = fmaf(tr[q].x, wb[q].x, b0);
            b0 = fmaf(tr[q].y, wb[q].y, b0);
            b0 = fmaf(tr[q].z, wb[q].z, b0);
            b0 = fmaf(tr[q].w, wb[q].w, b0);
            b1 = fmaf(tr[q + 1].x, wb[q + 1].x, b1);
            b1 = fmaf(tr[q + 1].y, wb[q + 1].y, b1);
            b1 = fmaf(tr[q + 1].z, wb[q + 1].z, b1);
            b1 = fmaf(tr[q + 1].w, wb[q + 1].w, b1);
        }
        float2 o;
        o.x = a0 + a1;
        o.y = b0 + b1;
        *reinterpret_cast<float2*>(orow + (size_t)r * kK) = o;
    }
}

// ---------------------------------------------------------------------------
// Fallback: round-1 fused kernel (proven correct) if ws too small.
// ---------------------------------------------------------------------------
__global__ __launch_bounds__(256, 2)
void gated_encoder_fused(const float* __restrict__ x,
                         const float* __restrict__ Wx,
                         const float* __restrict__ Wy,
                         const float* __restrict__ Wz,
                         float* __restrict__ out)
{
    __shared__ float t2[64][kF + 4];

    const int tid  = threadIdx.x;
    const int lane = tid & 63;
    const int wv   = tid >> 6;

    const int rloc = wv * 16 + (lane >> 2);
    const int row  = blockIdx.x * 64 + rloc;
    const int fg8  = (lane & 3) * 8;

    const float* __restrict__ xrow = x + (size_t)row * kJ;

    float acc[8];
#pragma unroll
    for (int u = 0; u < 8; ++u) acc[u] = 0.0f;

    for (int j = 0; j < kJ; j += 8) {
        const float4 xv0 = *reinterpret_cast<const float4*>(xrow + j);
        const float4 xv1 = *reinterpret_cast<const float4*>(xrow + j + 4);
        const float xs[8] = {xv0.x, xv0.y, xv0.z, xv0.w,
                             xv1.x, xv1.y, xv1.z, xv1.w};
#pragma unroll
        for (int u = 0; u < 8; ++u) {
            const float* wyp = Wy + (size_t)(j + u) * kF + fg8;
            const float4 w0 = *reinterpret_cast<const float4*>(wyp);
            const float4 w1 = *reinterpret_cast<const float4*>(wyp + 4);
            acc[0] = fmaf(xs[u], w0.x, acc[0]);
            acc[1] = fmaf(xs[u], w0.y, acc[1]);
            acc[2] = fmaf(xs[u], w0.z, acc[2]);
            acc[3] = fmaf(xs[u], w0.w, acc[3]);
            acc[4] = fmaf(xs[u], w1.x, acc[4]);
            acc[5] = fmaf(xs[u], w1.y, acc[5]);
            acc[6] = fmaf(xs[u], w1.z, acc[6]);
            acc[7] = fmaf(xs[u], w1.w, acc[7]);
        }
    }

    const int i = row & (kI - 1);
    const float* wxp = Wx + (size_t)i * kF + fg8;
    const float4 g0 = *reinterpret_cast<const float4*>(wxp);
    const float4 g1 = *reinterpret_cast<const float4*>(wxp + 4);
    float4 r0, r1;
    r0.x = acc[0] * g0.x;  r0.y = acc[1] * g0.y;
    r0.z = acc[2] * g0.z;  r0.w = acc[3] * g0.w;
    r1.x = acc[4] * g1.x;  r1.y = acc[5] * g1.y;
    r1.z = acc[6] * g1.z;  r1.w = acc[7] * g1.w;
    *reinterpret_cast<float4*>(&t2[rloc][fg8])     = r0;
    *reinterpret_cast<float4*>(&t2[rloc][fg8 + 4]) = r1;

    __syncthreads();

    const size_t outBase = (size_t)blockIdx.x * 64 * kK;

#pragma unroll
    for (int pass = 0; pass < 2; ++pass) {
        const int k1 = pass * 512 + tid;
        const int k2 = k1 + 256;
        const float* wz1 = Wz + (size_t)k1 * kF;
        const float* wz2 = Wz + (size_t)k2 * kF;
        float4 z1[8], z2[8];
#pragma unroll
        for (int m = 0; m < 8; ++m) {
            z1[m] = *reinterpret_cast<const float4*>(wz1 + 4 * m);
            z2[m] = *reinterpret_cast<const float4*>(wz2 + 4 * m);
        }
        for (int r = 0; r < 64; ++r) {
            float4 a1 = {0.f, 0.f, 0.f, 0.f};
            float4 a2 = {0.f, 0.f, 0.f, 0.f};
#pragma unroll
            for (int m = 0; m < 8; ++m) {
                const float4 tv = *reinterpret_cast<const float4*>(&t2[r][4 * m]);
                a1.x = fmaf(tv.x, z1[m].x, a1.x);
                a1.y = fmaf(tv.y, z1[m].y, a1.y);
                a1.z = fmaf(tv.z, z1[m].z, a1.z);
                a1.w = fmaf(tv.w, z1[m].w, a1.w);
                a2.x = fmaf(tv.x, z2[m].x, a2.x);
                a2.y = fmaf(tv.y, z2[m].y, a2.y);
                a2.z = fmaf(tv.z, z2[m].z, a2.z);
                a2.w = fmaf(tv.w, z2[m].w, a2.w);
            }
            out[outBase + (size_t)r * kK + k1] = (a1.x + a1.y) + (a1.z + a1.w);
            out[outBase + (size_t)r * kK + k2] = (a2.x + a2.y) + (a2.z + a2.w);
        }
    }
}

extern "C" void kernel_launch(void* const* d_in, const int* in_sizes, int n_in,
                              void* d_out, int out_size, void* d_ws, size_t ws_size,
                              hipStream_t stream) {
    const float* x  = (const float*)d_in[0];   // (B, I, J)
    const float* Wx = (const float*)d_in[1];   // (I, F)
    const float* Wy = (const float*)d_in[2];   // (J, F)
    const float* Wz = (const float*)d_in[3];   // (K, F)
    float* out = (float*)d_out;                // (B, I, K) f32

    const size_t tBytes  = (size_t)kRows * kF * sizeof(float);   // 4 MiB
    const size_t wyBytes = 8192 * sizeof(uint4);                 // 128 KiB

    if (ws_size >= tBytes + wyBytes && d_ws != nullptr) {
        float* t   = (float*)d_ws;
        uint4* wyp = (uint4*)((char*)d_ws + tBytes);
        ge_prepack<<<dim3(32), 256, 0, stream>>>(Wy, wyp);
        ge_stage1_mfma<<<dim3(kRows / 32), 256, 0, stream>>>(x, Wx, wyp, t);
        ge_stage2<<<dim3(kRows / 64), 512, 0, stream>>>(t, Wz, out);
    } else if (ws_size >= tBytes && d_ws != nullptr) {
        float* t = (float*)d_ws;
        ge_stage1_valu<<<dim3(kRows / 32), 256, 0, stream>>>(x, Wx, Wy, t);
        ge_stage2<<<dim3(kRows / 64), 512, 0, stream>>>(t, Wz, out);
    } else {
        gated_encoder_fused<<<dim3(kRows / 64), 256, 0, stream>>>(x, Wx, Wy, Wz, out);
    }
}

// Round 13
// 83.505 us; speedup vs baseline: 2.3095x; 1.0721x over previous
//
#include <hip/hip_runtime.h>
#include <hip/hip_bf16.h>
#include <string.h>

// GatedEncoderLayer: B=16, I=2048, J=1024, K=1024, F=32
// out[row,k] = sum_f [ (sum_j x[row,j]*Wy[j,f]) * Wx[row%I,f] ] * Wz[k,f]
constexpr int kI = 2048;
constexpr int kJ = 1024;
constexpr int kK = 1024;
constexpr int kF = 32;
constexpr int kRows = 16 * 2048;        // 32768

typedef __attribute__((ext_vector_type(8))) short short8v;
typedef __attribute__((ext_vector_type(4))) float f32x4;

__device__ inline unsigned short bf16_hi_bits(float v) {
    __hip_bfloat16 h = __float2bfloat16(v);      // RNE on gfx950
    unsigned short s;
    memcpy(&s, &h, 2);
    return s;
}
__device__ inline float bf16_bits_to_f(unsigned short s) {
    unsigned u = (unsigned)s << 16;
    float f;
    memcpy(&f, &u, 4);
    return f;
}
__device__ inline short8v as_s8(uint4 u) {
    union { uint4 a; short8v b; } c;
    c.a = u;
    return c.b;
}

// ---------------------------------------------------------------------------
// Prepack: Wy[1024][32] f32 -> fragment-ready packed bf16 hi/lo in d_ws.
// Entry e = ((ks*2 + ftile)*2 + h)*64 + lane ; 16 B each; 8192 entries=128 KB.
// Element p: bf16x2( Wy[ks*32+(lane>>4)*8+2p][f], ...[2p+1][f] ),
// f=(lane&15)+ftile*16; h=0 hi, h=1 lo. Same (group,elem)->j map as the
// x-fragment loader => contraction correct for ANY internal HW k-order.
// 64 blocks (was 32): spread scattered loads over more CUs.
// ---------------------------------------------------------------------------
__global__ __launch_bounds__(128)
void ge_prepack(const float* __restrict__ Wy, uint4* __restrict__ wyp)
{
    const int e  = blockIdx.x * 128 + threadIdx.x;   // 0..8191
    const int l  = e & 63;
    const int h  = (e >> 6) & 1;
    const int tf = (e >> 7) & 1;
    const int ks = e >> 8;
    const int f  = (l & 15) + tf * 16;
    const int j0 = ks * 32 + (l >> 4) * 8;

    unsigned d[4];
#pragma unroll
    for (int p = 0; p < 4; ++p) {
        const float v0 = Wy[(size_t)(j0 + 2 * p) * kF + f];
        const float v1 = Wy[(size_t)(j0 + 2 * p + 1) * kF + f];
        unsigned short s0, s1;
        if (h == 0) {
            s0 = bf16_hi_bits(v0);
            s1 = bf16_hi_bits(v1);
        } else {
            s0 = bf16_hi_bits(v0 - bf16_bits_to_f(bf16_hi_bits(v0)));
            s1 = bf16_hi_bits(v1 - bf16_bits_to_f(bf16_hi_bits(v1)));
        }
        d[p] = (unsigned)s0 | ((unsigned)s1 << 16);
    }
    wyp[e] = make_uint4(d[0], d[1], d[2], d[3]);
}

// ---------------------------------------------------------------------------
// Stage 1 (MFMA + LDS-staged x): t[row,f] = (sum_j x[row,j]*Wy[j,f])*Wx[i,f]
// Rounds 11/12: per-lane x fragment loads (16 rows x 2 lines = 32 cache lines
// per instr) were wave-count-insensitive stall (~98%) -> MSHR/drain bound.
// Fix (m97/T14 pattern): x tile [64 rows][128 j] staged via COALESCED global
// float4 loads (512B runs) -> regs -> ds_write; double-buffered, ONE barrier
// per tile; loads for tile c+1 issue BEFORE compute(c) (latency hides under
// 4 K-steps of cvt+MFMA), ds_write after.  Fragments via ds_read_b128 from
// padded stride-132 rows: bank-group (m+2g)%8 uniform -> optimal 8-phase.
// LDS 2x33.8KB -> 2 blocks/CU. 512 blocks x 256 thr (4 waves x 16 rows).
// bf16-split: x*w ~= xh*wh + xh*wl + xl*wh (xl*wl dropped ~2^-18 rel).
// D layout (verified m89): n=lane&15, m=(lane>>4)*4+reg.
// ---------------------------------------------------------------------------
__global__ __launch_bounds__(256, 2)
void ge_stage1_mfma(const float* __restrict__ x,
                    const float* __restrict__ Wx,
                    const uint4* __restrict__ wyp,
                    float* __restrict__ t)
{
    __shared__ float xbuf[2][64 * 132];  // 2 x 33.8 KB, row stride 132 floats

    const int tid  = threadIdx.x;
    const int lane = tid & 63;
    const int wv   = tid >> 6;           // wave 0..3 = row-group
    const int mrow = lane & 15;
    const int g    = lane >> 4;
    const int rowBase = blockIdx.x * 64;

    // staging coords: thread covers col sc (fixed), rows sr0 + p*8
    const int sr0 = tid >> 5;            // 0..7
    const int sc  = (tid & 31) * 4;      // float col 0..124

    const uint4* __restrict__ bp = wyp + lane;
    const int lbase = (wv * 16 + mrow) * 132 + g * 8;

    f32x4 c0 = {0.f, 0.f, 0.f, 0.f};
    f32x4 c1 = {0.f, 0.f, 0.f, 0.f};
    float4 sreg[8];

#define SLOAD(ti)                                                       \
    _Pragma("unroll")                                                   \
    for (int p = 0; p < 8; ++p)                                         \
        sreg[p] = *reinterpret_cast<const float4*>(                     \
            x + (size_t)(rowBase + sr0 + p * 8) * kJ + (ti) * 128 + sc);

#define SWRITE(b)                                                       \
    _Pragma("unroll")                                                   \
    for (int p = 0; p < 8; ++p)                                         \
        *reinterpret_cast<float4*>(                                     \
            &xbuf[b][(sr0 + p * 8) * 132 + sc]) = sreg[p];

    SLOAD(0)
    SWRITE(0)
    __syncthreads();

#pragma unroll
    for (int ti = 0; ti < 8; ++ti) {
        if (ti < 7) { SLOAD(ti + 1) }           // issue early (T14)

#pragma unroll
        for (int kk = 0; kk < 4; ++kk) {        // K-steps within tile
            const int ks = ti * 4 + kk;
            const uint4 b0h = bp[(size_t)(ks * 4 + 0) * 64];
            const uint4 b0l = bp[(size_t)(ks * 4 + 1) * 64];
            const uint4 b1h = bp[(size_t)(ks * 4 + 2) * 64];
            const uint4 b1l = bp[(size_t)(ks * 4 + 3) * 64];

            const float4 xa = *reinterpret_cast<const float4*>(
                &xbuf[ti & 1][lbase + kk * 32]);
            const float4 xb = *reinterpret_cast<const float4*>(
                &xbuf[ti & 1][lbase + kk * 32 + 4]);
            const float xv[8] = {xa.x, xa.y, xa.z, xa.w,
                                 xb.x, xb.y, xb.z, xb.w};

            short8v ah, al;
#pragma unroll
            for (int e = 0; e < 8; ++e) {
                const unsigned short hb = bf16_hi_bits(xv[e]);
                const float hf = bf16_bits_to_f(hb);
                const unsigned short lb = bf16_hi_bits(xv[e] - hf);
                ah[e] = (short)hb;
                al[e] = (short)lb;
            }

            c0 = __builtin_amdgcn_mfma_f32_16x16x32_bf16(ah, as_s8(b0h), c0, 0, 0, 0);
            c1 = __builtin_amdgcn_mfma_f32_16x16x32_bf16(ah, as_s8(b1h), c1, 0, 0, 0);
            c0 = __builtin_amdgcn_mfma_f32_16x16x32_bf16(ah, as_s8(b0l), c0, 0, 0, 0);
            c1 = __builtin_amdgcn_mfma_f32_16x16x32_bf16(ah, as_s8(b1l), c1, 0, 0, 0);
            c0 = __builtin_amdgcn_mfma_f32_16x16x32_bf16(al, as_s8(b0h), c0, 0, 0, 0);
            c1 = __builtin_amdgcn_mfma_f32_16x16x32_bf16(al, as_s8(b1h), c1, 0, 0, 0);
        }

        if (ti < 7) {
            SWRITE((ti + 1) & 1)                // vmcnt wait lands here
            __syncthreads();                    // one barrier per tile
        }
    }

    // epilogue: gate by Wx, store. D: n=lane&15, m=(lane>>4)*4+reg.
    const int n = lane & 15;
#pragma unroll
    for (int r = 0; r < 4; ++r) {
        const int row = rowBase + wv * 16 + g * 4 + r;
        const int i   = row & (kI - 1);
        t[(size_t)row * kF + n]      = c0[r] * Wx[(size_t)i * kF + n];
        t[(size_t)row * kF + 16 + n] = c1[r] * Wx[(size_t)i * kF + 16 + n];
    }
#undef SLOAD
#undef SWRITE
}

// ---------------------------------------------------------------------------
// Stage 1 (VALU fallback, ~83 us): used if ws lacks wyp room.
// ---------------------------------------------------------------------------
constexpr int kCJ = 256;

#define LOADW(buf, jabs)                                               \
    _Pragma("unroll")                                                  \
    for (int r = 0; r < 8; ++r)                                        \
        buf[r] = *reinterpret_cast<const float4*>(                     \
            xrow0 + (size_t)r * kJ + (jabs));

#define COMPW(buf, jl)                                                 \
    _Pragma("unroll")                                                  \
    for (int u = 0; u < 4; ++u) {                                      \
        const float4 wv = *reinterpret_cast<const float4*>(            \
            &wyb[(((jl) + jo * 4 + u) * 8 + fq) * 4]);                 \
        _Pragma("unroll")                                              \
        for (int r = 0; r < 8; ++r) {                                  \
            const float xs = (u == 0) ? buf[r].x : (u == 1) ? buf[r].y \
                           : (u == 2) ? buf[r].z : buf[r].w;           \
            acc[r].x = fmaf(xs, wv.x, acc[r].x);                       \
            acc[r].y = fmaf(xs, wv.y, acc[r].y);                       \
            acc[r].z = fmaf(xs, wv.z, acc[r].z);                       \
            acc[r].w = fmaf(xs, wv.w, acc[r].w);                       \
        }                                                              \
    }

#define STEP(bc, bp, gw, wd)                                           \
    if ((gw) + 2 < 32) { LOADW(bp, ((gw) + 2) * 32) }                  \
    COMPW(bc, (wd) * 32)

__global__ __launch_bounds__(256, 2)
void ge_stage1_valu(const float* __restrict__ x,
                    const float* __restrict__ Wx,
                    const float* __restrict__ Wy,
                    float* __restrict__ t)
{
    __shared__ float wyb[kCJ * kF];

    const int tid  = threadIdx.x;
    const int lane = tid & 63;
    const int w    = tid >> 6;
    const int fq   = lane & 7;
    const int jo   = lane >> 3;
    const int rowBase = blockIdx.x * 32 + w * 8;

    const float* __restrict__ xrow0 = x + (size_t)rowBase * kJ + jo * 4;

    float4 acc[8];
#pragma unroll
    for (int r = 0; r < 8; ++r) acc[r] = make_float4(0.f, 0.f, 0.f, 0.f);

    float4 x0[8], x1[8], x2[8];
    LOADW(x0, 0)
    LOADW(x1, 32)

#pragma unroll
    for (int c = 0; c < 4; ++c) {
        __syncthreads();
        {
            const float4* src = reinterpret_cast<const float4*>(
                Wy + (size_t)c * kCJ * kF);
            float4* dst = reinterpret_cast<float4*>(wyb);
#pragma unroll
            for (int p = 0; p < 8; ++p)
                dst[tid + p * 256] = src[tid + p * 256];
        }
        __syncthreads();

#pragma unroll
        for (int wd = 0; wd < 8; ++wd) {
            const int gw = c * 8 + wd;
            const int ph = gw % 3;
            if (ph == 0)      { STEP(x0, x2, gw, wd) }
            else if (ph == 1) { STEP(x1, x0, gw, wd) }
            else              { STEP(x2, x1, gw, wd) }
        }
    }

    float4 ov = make_float4(0.f, 0.f, 0.f, 0.f);
#pragma unroll
    for (int r = 0; r < 8; ++r) {
        float4 v = acc[r];
        v.x += __shfl_xor(v.x, 8);  v.y += __shfl_xor(v.y, 8);
        v.z += __shfl_xor(v.z, 8);  v.w += __shfl_xor(v.w, 8);
        v.x += __shfl_xor(v.x, 16); v.y += __shfl_xor(v.y, 16);
        v.z += __shfl_xor(v.z, 16); v.w += __shfl_xor(v.w, 16);
        v.x += __shfl_xor(v.x, 32); v.y += __shfl_xor(v.y, 32);
        v.z += __shfl_xor(v.z, 32); v.w += __shfl_xor(v.w, 32);
        if (jo == r) ov = v;
    }

    const int f0  = fq * 4;
    const int row = rowBase + jo;
    const int i   = row & (kI - 1);
    const float4 g = *reinterpret_cast<const float4*>(Wx + (size_t)i * kF + f0);
    ov.x *= g.x; ov.y *= g.y; ov.z *= g.z; ov.w *= g.w;
    *reinterpret_cast<float4*>(t + (size_t)row * kF + f0) = ov;
}

// ---------------------------------------------------------------------------
// Stage 2: out[row,k] = sum_f t[row,f] * Wz[k,f]   (~28 us measured, round 5)
// ---------------------------------------------------------------------------
__global__ __launch_bounds__(512, 2)
void ge_stage2(const float* __restrict__ t,
               const float* __restrict__ Wz,
               float* __restrict__ out)
{
    __shared__ float t2[64][kF];

    const int tid = threadIdx.x;
    const int rowBase = blockIdx.x * 64;

    reinterpret_cast<float4*>(&t2[0][0])[tid] =
        reinterpret_cast<const float4*>(t + (size_t)rowBase * kF)[tid];

    const int k0 = tid * 2;
    float4 wa[8], wb[8];
#pragma unroll
    for (int q = 0; q < 8; ++q) {
        wa[q] = *reinterpret_cast<const float4*>(Wz + (size_t)k0 * kF + q * 4);
        wb[q] = *reinterpret_cast<const float4*>(Wz + (size_t)(k0 + 1) * kF + q * 4);
    }
    __syncthreads();

    float* __restrict__ orow = out + (size_t)rowBase * kK + k0;

    for (int r = 0; r < 64; ++r) {
        float4 tr[8];
#pragma unroll
        for (int q = 0; q < 8; ++q)
            tr[q] = *reinterpret_cast<const float4*>(&t2[r][q * 4]);

        float a0 = 0.f, a1 = 0.f, b0 = 0.f, b1 = 0.f;
#pragma unroll
        for (int q = 0; q < 8; q += 2) {
            a0 = fmaf(tr[q].x, wa[q].x, a0);
            a0 = fmaf(tr[q].y, wa[q].y, a0);
            a0 = fmaf(tr[q].z, wa[q].z, a0);
            a0 = fmaf(tr[q].w, wa[q].w, a0);
            a1 = fmaf(tr[q + 1].x, wa[q + 1].x, a1);
            a1 = fmaf(tr[q + 1].y, wa[q + 1].y, a1);
            a1 = fmaf(tr[q + 1].z, wa[q + 1].z, a1);
            a1 = fmaf(tr[q + 1].w, wa[q + 1].w, a1);
            b0 = fmaf(tr[q].x, wb[q].x, b0);
            b0 = fmaf(tr[q].y, wb[q].y, b0);
            b0 = fmaf(tr[q].z, wb[q].z, b0);
            b0 = fmaf(tr[q].w, wb[q].w, b0);
            b1 = fmaf(tr[q + 1].x, wb[q + 1].x, b1);
            b1 = fmaf(tr[q + 1].y, wb[q + 1].y, b1);
            b1 = fmaf(tr[q + 1].z, wb[q + 1].z, b1);
            b1 = fmaf(tr[q + 1].w, wb[q + 1].w, b1);
        }
        float2 o;
        o.x = a0 + a1;
        o.y = b0 + b1;
        *reinterpret_cast<float2*>(orow + (size_t)r * kK) = o;
    }
}

// ---------------------------------------------------------------------------
// Fallback: round-1 fused kernel (proven correct) if ws too small.
// ---------------------------------------------------------------------------
__global__ __launch_bounds__(256, 2)
void gated_encoder_fused(const float* __restrict__ x,
                         const float* __restrict__ Wx,
                         const float* __restrict__ Wy,
                         const float* __restrict__ Wz,
                         float* __restrict__ out)
{
    __shared__ float t2[64][kF + 4];

    const int tid  = threadIdx.x;
    const int lane = tid & 63;
    const int wv   = tid >> 6;

    const int rloc = wv * 16 + (lane >> 2);
    const int row  = blockIdx.x * 64 + rloc;
    const int fg8  = (lane & 3) * 8;

    const float* __restrict__ xrow = x + (size_t)row * kJ;

    float acc[8];
#pragma unroll
    for (int u = 0; u < 8; ++u) acc[u] = 0.0f;

    for (int j = 0; j < kJ; j += 8) {
        const float4 xv0 = *reinterpret_cast<const float4*>(xrow + j);
        const float4 xv1 = *reinterpret_cast<const float4*>(xrow + j + 4);
        const float xs[8] = {xv0.x, xv0.y, xv0.z, xv0.w,
                             xv1.x, xv1.y, xv1.z, xv1.w};
#pragma unroll
        for (int u = 0; u < 8; ++u) {
            const float* wyp = Wy + (size_t)(j + u) * kF + fg8;
            const float4 w0 = *reinterpret_cast<const float4*>(wyp);
            const float4 w1 = *reinterpret_cast<const float4*>(wyp + 4);
            acc[0] = fmaf(xs[u], w0.x, acc[0]);
            acc[1] = fmaf(xs[u], w0.y, acc[1]);
            acc[2] = fmaf(xs[u], w0.z, acc[2]);
            acc[3] = fmaf(xs[u], w0.w, acc[3]);
            acc[4] = fmaf(xs[u], w1.x, acc[4]);
            acc[5] = fmaf(xs[u], w1.y, acc[5]);
            acc[6] = fmaf(xs[u], w1.z, acc[6]);
            acc[7] = fmaf(xs[u], w1.w, acc[7]);
        }
    }

    const int i = row & (kI - 1);
    const float* wxp = Wx + (size_t)i * kF + fg8;
    const float4 g0 = *reinterpret_cast<const float4*>(wxp);
    const float4 g1 = *reinterpret_cast<const float4*>(wxp + 4);
    float4 r0, r1;
    r0.x = acc[0] * g0.x;  r0.y = acc[1] * g0.y;
    r0.z = acc[2] * g0.z;  r0.w = acc[3] * g0.w;
    r1.x = acc[4] * g1.x;  r1.y = acc[5] * g1.y;
    r1.z = acc[6] * g1.z;  r1.w = acc[7] * g1.w;
    *reinterpret_cast<float4*>(&t2[rloc][fg8])     = r0;
    *reinterpret_cast<float4*>(&t2[rloc][fg8 + 4]) = r1;

    __syncthreads();

    const size_t outBase = (size_t)blockIdx.x * 64 * kK;

#pragma unroll
    for (int pass = 0; pass < 2; ++pass) {
        const int k1 = pass * 512 + tid;
        const int k2 = k1 + 256;
        const float* wz1 = Wz + (size_t)k1 * kF;
        const float* wz2 = Wz + (size_t)k2 * kF;
        float4 z1[8], z2[8];
#pragma unroll
        for (int m = 0; m < 8; ++m) {
            z1[m] = *reinterpret_cast<const float4*>(wz1 + 4 * m);
            z2[m] = *reinterpret_cast<const float4*>(wz2 + 4 * m);
        }
        for (int r = 0; r < 64; ++r) {
            float4 a1 = {0.f, 0.f, 0.f, 0.f};
            float4 a2 = {0.f, 0.f, 0.f, 0.f};
#pragma unroll
            for (int m = 0; m < 8; ++m) {
                const float4 tv = *reinterpret_cast<const float4*>(&t2[r][4 * m]);
                a1.x = fmaf(tv.x, z1[m].x, a1.x);
                a1.y = fmaf(tv.y, z1[m].y, a1.y);
                a1.z = fmaf(tv.z, z1[m].z, a1.z);
                a1.w = fmaf(tv.w, z1[m].w, a1.w);
                a2.x = fmaf(tv.x, z2[m].x, a2.x);
                a2.y = fmaf(tv.y, z2[m].y, a2.y);
                a2.z = fmaf(tv.z, z2[m].z, a2.z);
                a2.w = fmaf(tv.w, z2[m].w, a2.w);
            }
            out[outBase + (size_t)r * kK + k1] = (a1.x + a1.y) + (a1.z + a1.w);
            out[outBase + (size_t)r * kK + k2] = (a2.x + a2.y) + (a2.z + a2.w);
        }
    }
}

extern "C" void kernel_launch(void* const* d_in, const int* in_sizes, int n_in,
                              void* d_out, int out_size, void* d_ws, size_t ws_size,
                              hipStream_t stream) {
    const float* x  = (const float*)d_in[0];   // (B, I, J)
    const float* Wx = (const float*)d_in[1];   // (I, F)
    const float* Wy = (const float*)d_in[2];   // (J, F)
    const float* Wz = (const float*)d_in[3];   // (K, F)
    float* out = (float*)d_out;                // (B, I, K) f32

    const size_t tBytes  = (size_t)kRows * kF * sizeof(float);   // 4 MiB
    const size_t wyBytes = 8192 * sizeof(uint4);                 // 128 KiB

    if (ws_size >= tBytes + wyBytes && d_ws != nullptr) {
        float* t   = (float*)d_ws;
        uint4* wyp = (uint4*)((char*)d_ws + tBytes);
        ge_prepack<<<dim3(64), 128, 0, stream>>>(Wy, wyp);
        ge_stage1_mfma<<<dim3(kRows / 64), 256, 0, stream>>>(x, Wx, wyp, t);
        ge_stage2<<<dim3(kRows / 64), 512, 0, stream>>>(t, Wz, out);
    } else if (ws_size >= tBytes && d_ws != nullptr) {
        float* t = (float*)d_ws;
        ge_stage1_valu<<<dim3(kRows / 32), 256, 0, stream>>>(x, Wx, Wy, t);
        ge_stage2<<<dim3(kRows / 64), 512, 0, stream>>>(t, Wz, out);
    } else {
        gated_encoder_fused<<<dim3(kRows / 64), 256, 0, stream>>>(x, Wx, Wy, Wz, out);
    }
}